// Round 3
// baseline (871.266 us; speedup 1.0000x reference)
//
#include <hip/hip_runtime.h>
#include <hip/hip_bf16.h>

#define N_NODES 20000
#define N_EDGES 320000
#define IN_DIM 256
#define HID 128
#define HEADS 4

// ---------------------------------------------------------------------------
// CSR build: histogram -> scan -> scatter
// ---------------------------------------------------------------------------
__global__ void hist_kernel(const int* __restrict__ dst, int* __restrict__ deg, int E) {
    int i = blockIdx.x * blockDim.x + threadIdx.x;
    if (i < E) atomicAdd(&deg[dst[i]], 1);
}

__global__ void scan_kernel(const int* __restrict__ deg, int* __restrict__ row_start,
                            int* __restrict__ cursor, int n) {
    // single block, 256 threads
    __shared__ int partial[256];
    int t = threadIdx.x;
    int chunk = (n + 255) / 256;
    int begin = t * chunk;
    int end = min(begin + chunk, n);
    int s = 0;
    for (int i = begin; i < end; ++i) s += deg[i];
    partial[t] = s;
    __syncthreads();
    // Hillis-Steele inclusive scan
    for (int off = 1; off < 256; off <<= 1) {
        int v = (t >= off) ? partial[t - off] : 0;
        __syncthreads();
        partial[t] += v;
        __syncthreads();
    }
    int run = (t == 0) ? 0 : partial[t - 1];
    for (int i = begin; i < end; ++i) {
        row_start[i] = run;
        cursor[i] = run;
        run += deg[i];
    }
    if (t == 255) row_start[n] = run;   // == E
}

__global__ void scatter_kernel(const int* __restrict__ src, const int* __restrict__ dst,
                               int* __restrict__ cursor, int* __restrict__ ssrc,
                               int* __restrict__ sdst, int E) {
    int i = blockIdx.x * blockDim.x + threadIdx.x;
    if (i < E) {
        int d = dst[i];
        int pos = atomicAdd(&cursor[d], 1);
        ssrc[pos] = src[i];
        sdst[pos] = d;
    }
}

// ---------------------------------------------------------------------------
// fp32 tiled GEMM with bias: C[M,N] = A[M,K] @ B[K,N] + bias[N]
// BM=128 BN=64 BK=16, 256 threads, 8x4 per thread
// ---------------------------------------------------------------------------
__global__ __launch_bounds__(256) void gemm_bias_kernel(
    const float* __restrict__ A, const float* __restrict__ B,
    const float* __restrict__ bias, float* __restrict__ C,
    int M, int N, int K) {
    __shared__ __align__(16) float As[16][128 + 4];
    __shared__ __align__(16) float Bs[16][64 + 4];
    int tid = threadIdx.x;
    int brow = blockIdx.y * 128;
    int bcol = blockIdx.x * 64;
    int tr = (tid >> 4) * 8;
    int tc = (tid & 15) * 4;
    float acc[8][4] = {};
    for (int k0 = 0; k0 < K; k0 += 16) {
        #pragma unroll
        for (int i = 0; i < 8; ++i) {
            int idx = tid + i * 256;        // 0..2047
            int r = idx >> 4, c = idx & 15;
            int gr = brow + r;
            As[c][r] = (gr < M) ? A[(size_t)gr * K + k0 + c] : 0.f;
        }
        #pragma unroll
        for (int i = 0; i < 4; ++i) {
            int idx = tid + i * 256;        // 0..1023
            int r = idx >> 6, c = idx & 63;
            Bs[r][c] = B[(size_t)(k0 + r) * N + bcol + c];
        }
        __syncthreads();
        #pragma unroll
        for (int kk = 0; kk < 16; ++kk) {
            float4 b4 = *(const float4*)&Bs[kk][tc];
            float4 a0 = *(const float4*)&As[kk][tr];
            float4 a1 = *(const float4*)&As[kk][tr + 4];
            float a[8] = {a0.x, a0.y, a0.z, a0.w, a1.x, a1.y, a1.z, a1.w};
            float b[4] = {b4.x, b4.y, b4.z, b4.w};
            #pragma unroll
            for (int i = 0; i < 8; ++i)
                #pragma unroll
                for (int j = 0; j < 4; ++j)
                    acc[i][j] += a[i] * b[j];
        }
        __syncthreads();
    }
    float4 bb = *(const float4*)&bias[bcol + tc];
    #pragma unroll
    for (int i = 0; i < 8; ++i) {
        int gr = brow + tr + i;
        if (gr < M) {
            float4 v;
            v.x = acc[i][0] + bb.x; v.y = acc[i][1] + bb.y;
            v.z = acc[i][2] + bb.z; v.w = acc[i][3] + bb.w;
            *(float4*)&C[(size_t)gr * N + bcol + tc] = v;
        }
    }
}

// ---------------------------------------------------------------------------
// Layer-1 edge scores: one wave per (sorted) edge; 4 heads x 128 ch
// score[e*4+h] = sum_c lrelu(xl[s,h,c]+xr[d,h,c]) * att1[h,c]
// ---------------------------------------------------------------------------
__global__ __launch_bounds__(256) void score1_kernel(
    const float* __restrict__ xl, const float* __restrict__ xr,
    const int* __restrict__ ssrc, const int* __restrict__ sdst,
    const float* __restrict__ att1, float* __restrict__ score, int E) {
    int e = blockIdx.x * 4 + (threadIdx.x >> 6);
    int lane = threadIdx.x & 63;
    if (e >= E) return;
    int s = ssrc[e], d = sdst[e];
    const float4* pl = (const float4*)(xl + (size_t)s * 512);
    const float4* pr = (const float4*)(xr + (size_t)d * 512);
    const float4* pa = (const float4*)att1;
    float acc = 0.f;
    #pragma unroll
    for (int q = 0; q < 2; ++q) {
        float4 l = pl[lane * 2 + q];
        float4 r = pr[lane * 2 + q];
        float4 w = pa[lane * 2 + q];
        float vx = l.x + r.x; vx = vx > 0.f ? vx : 0.2f * vx;
        float vy = l.y + r.y; vy = vy > 0.f ? vy : 0.2f * vy;
        float vz = l.z + r.z; vz = vz > 0.f ? vz : 0.2f * vz;
        float vw = l.w + r.w; vw = vw > 0.f ? vw : 0.2f * vw;
        acc += vx * w.x + vy * w.y + vz * w.z + vw * w.w;
    }
    // reduce within 16-lane (per-head) groups
    acc += __shfl_xor(acc, 1);
    acc += __shfl_xor(acc, 2);
    acc += __shfl_xor(acc, 4);
    acc += __shfl_xor(acc, 8);
    if ((lane & 15) == 0) score[(size_t)e * 4 + (lane >> 4)] = acc;
}

// ---------------------------------------------------------------------------
// Layer-1 aggregation: block per node, wave per head. softmax over incoming
// edges, accumulate alpha * xl[src], + bias1, ELU -> h1
// ---------------------------------------------------------------------------
__global__ __launch_bounds__(256) void agg1_kernel(
    const float* __restrict__ xl, const float* __restrict__ score,
    const int* __restrict__ row_start, const int* __restrict__ ssrc,
    const float* __restrict__ bias1, float* __restrict__ h1, int n) {
    int node = blockIdx.x;
    int wid = threadIdx.x >> 6;   // head
    int lane = threadIdx.x & 63;
    int beg = row_start[node], end = row_start[node + 1];
    float m = -3.402823466e38f;
    for (int p = beg + lane; p < end; p += 64)
        m = fmaxf(m, score[(size_t)p * 4 + wid]);
    #pragma unroll
    for (int off = 1; off < 64; off <<= 1) m = fmaxf(m, __shfl_xor(m, off));
    float ssum = 0.f;
    for (int p = beg + lane; p < end; p += 64)
        ssum += __expf(score[(size_t)p * 4 + wid] - m);
    #pragma unroll
    for (int off = 1; off < 64; off <<= 1) ssum += __shfl_xor(ssum, off);
    float inv = 1.f / (ssum + 1e-16f);
    float acc0 = 0.f, acc1 = 0.f;
    for (int p = beg; p < end; ++p) {
        float a = __expf(score[(size_t)p * 4 + wid] - m) * inv;
        const float* px = xl + (size_t)ssrc[p] * 512 + wid * 128;
        acc0 += a * px[lane];
        acc1 += a * px[lane + 64];
    }
    int c = wid * 128 + lane;
    float v0 = acc0 + bias1[c];
    float v1 = acc1 + bias1[c + 64];
    v0 = v0 > 0.f ? v0 : __expf(v0) - 1.f;   // ELU
    v1 = v1 > 0.f ? v1 : __expf(v1) - 1.f;
    h1[(size_t)node * 512 + c] = v0;
    h1[(size_t)node * 512 + c + 64] = v1;
}

// ---------------------------------------------------------------------------
// Layer-2 edge scores: one wave per edge, 128 ch
// ---------------------------------------------------------------------------
__global__ __launch_bounds__(256) void score2_kernel(
    const float* __restrict__ xl2, const float* __restrict__ xr2,
    const int* __restrict__ ssrc, const int* __restrict__ sdst,
    const float* __restrict__ att2, float* __restrict__ score2, int E) {
    int e = blockIdx.x * 4 + (threadIdx.x >> 6);
    int lane = threadIdx.x & 63;
    if (e >= E) return;
    int s = ssrc[e], d = sdst[e];
    const float2* pl = (const float2*)(xl2 + (size_t)s * 128);
    const float2* pr = (const float2*)(xr2 + (size_t)d * 128);
    const float2* pa = (const float2*)att2;
    float2 l = pl[lane], r = pr[lane], w = pa[lane];
    float ax = l.x + r.x; ax = ax > 0.f ? ax : 0.2f * ax;
    float ay = l.y + r.y; ay = ay > 0.f ? ay : 0.2f * ay;
    float acc = ax * w.x + ay * w.y;
    #pragma unroll
    for (int off = 1; off < 64; off <<= 1) acc += __shfl_xor(acc, off);
    if (lane == 0) score2[e] = acc;
}

// ---------------------------------------------------------------------------
// Layer-2 aggregation: wave per node, 1 head, 128 ch, + bias2 -> h2
// ---------------------------------------------------------------------------
__global__ __launch_bounds__(256) void agg2_kernel(
    const float* __restrict__ xl2, const float* __restrict__ score2,
    const int* __restrict__ row_start, const int* __restrict__ ssrc,
    const float* __restrict__ bias2, float* __restrict__ h2, int n) {
    int node = blockIdx.x * 4 + (threadIdx.x >> 6);
    int lane = threadIdx.x & 63;
    if (node >= n) return;
    int beg = row_start[node], end = row_start[node + 1];
    float m = -3.402823466e38f;
    for (int p = beg + lane; p < end; p += 64) m = fmaxf(m, score2[p]);
    #pragma unroll
    for (int off = 1; off < 64; off <<= 1) m = fmaxf(m, __shfl_xor(m, off));
    float ssum = 0.f;
    for (int p = beg + lane; p < end; p += 64) ssum += __expf(score2[p] - m);
    #pragma unroll
    for (int off = 1; off < 64; off <<= 1) ssum += __shfl_xor(ssum, off);
    float inv = 1.f / (ssum + 1e-16f);
    float acc0 = 0.f, acc1 = 0.f;
    for (int p = beg; p < end; ++p) {
        float a = __expf(score2[p] - m) * inv;
        const float* px = xl2 + (size_t)ssrc[p] * 128;
        acc0 += a * px[lane];
        acc1 += a * px[lane + 64];
    }
    h2[(size_t)node * 128 + lane] = acc0 + bias2[lane];
    h2[(size_t)node * 128 + lane + 64] = acc1 + bias2[lane + 64];
}

// ---------------------------------------------------------------------------
// Heads: wave per node, two 128-dots + sigmoid
// ---------------------------------------------------------------------------
__global__ __launch_bounds__(256) void heads_kernel(
    const float* __restrict__ h2, const float* __restrict__ Wa,
    const float* __restrict__ ba, const float* __restrict__ Wrc,
    const float* __restrict__ brc, float* __restrict__ out, int n) {
    int node = blockIdx.x * 4 + (threadIdx.x >> 6);
    int lane = threadIdx.x & 63;
    if (node >= n) return;
    const float* p = h2 + (size_t)node * 128;
    float v0 = p[lane], v1 = p[lane + 64];
    float a = v0 * Wa[lane] + v1 * Wa[lane + 64];
    float r = v0 * Wrc[lane] + v1 * Wrc[lane + 64];
    #pragma unroll
    for (int off = 1; off < 64; off <<= 1) {
        a += __shfl_xor(a, off);
        r += __shfl_xor(r, off);
    }
    if (lane == 0) {
        out[node]     = 1.f / (1.f + __expf(-(a + ba[0])));
        out[n + node] = 1.f / (1.f + __expf(-(r + brc[0])));
    }
}

// ---------------------------------------------------------------------------
extern "C" void kernel_launch(void* const* d_in, const int* in_sizes, int n_in,
                              void* d_out, int out_size, void* d_ws, size_t ws_size,
                              hipStream_t stream) {
    const float* x    = (const float*)d_in[0];
    const int* ei     = (const int*)d_in[1];
    const float* W1l  = (const float*)d_in[2];
    const float* b1l  = (const float*)d_in[3];
    const float* W1r  = (const float*)d_in[4];
    const float* b1r  = (const float*)d_in[5];
    const float* att1 = (const float*)d_in[6];
    const float* bias1= (const float*)d_in[7];
    const float* W2l  = (const float*)d_in[8];
    const float* b2l  = (const float*)d_in[9];
    const float* W2r  = (const float*)d_in[10];
    const float* b2r  = (const float*)d_in[11];
    const float* att2 = (const float*)d_in[12];
    const float* bias2= (const float*)d_in[13];
    const float* Wa   = (const float*)d_in[14];
    const float* ba   = (const float*)d_in[15];
    const float* Wrc  = (const float*)d_in[16];
    const float* brc  = (const float*)d_in[17];
    float* out = (float*)d_out;

    const int N = N_NODES, E = N_EDGES;
    const int* src = ei;
    const int* dst = ei + E;

    char* ws = (char*)d_ws;
    // region A (41 MB): xl1, later reused for layer-2 buffers
    float* xl1 = (float*)ws;                          // 20000*512*4 = 40,960,000
    float* xl2 = (float*)ws;                          // 10,240,000 (after xl1 dead)
    float* xr2 = (float*)(ws + 10240000);             // 10,240,000
    float* h2  = (float*)(ws + 20480000);             // 10,240,000
    float* sc2 = (float*)(ws + 30720000);             //  1,280,000
    // region B (41 MB): xr1, later reused as h1
    float* xr1 = (float*)(ws + 40960000);
    float* h1  = xr1;
    float* sc1 = (float*)(ws + 81920000);             //  5,120,000
    int* deg       = (int*)(ws + 87040000);           //     80,000
    int* row_start = (int*)(ws + 87120128);           //     80,004
    int* cursor    = (int*)(ws + 87200384);           //     80,000
    int* ssrc      = (int*)(ws + 87280640);           //  1,280,000
    int* sdst      = (int*)(ws + 88560640);           //  1,280,000
    // total: 89,840,640 bytes

    // --- CSR build ---
    hipMemsetAsync(deg, 0, N * sizeof(int), stream);
    hist_kernel<<<(E + 255) / 256, 256, 0, stream>>>(dst, deg, E);
    scan_kernel<<<1, 256, 0, stream>>>(deg, row_start, cursor, N);
    scatter_kernel<<<(E + 255) / 256, 256, 0, stream>>>(src, dst, cursor, ssrc, sdst, E);

    // --- layer 1 ---
    dim3 g1(512 / 64, (N + 127) / 128);
    gemm_bias_kernel<<<g1, 256, 0, stream>>>(x, W1l, b1l, xl1, N, 512, IN_DIM);
    gemm_bias_kernel<<<g1, 256, 0, stream>>>(x, W1r, b1r, xr1, N, 512, IN_DIM);
    score1_kernel<<<(E + 3) / 4, 256, 0, stream>>>(xl1, xr1, ssrc, sdst, att1, sc1, E);
    agg1_kernel<<<N, 256, 0, stream>>>(xl1, sc1, row_start, ssrc, bias1, h1, N);

    // --- layer 2 ---
    dim3 g2(128 / 64, (N + 127) / 128);
    gemm_bias_kernel<<<g2, 256, 0, stream>>>(h1, W2l, b2l, xl2, N, 128, 512);
    gemm_bias_kernel<<<g2, 256, 0, stream>>>(h1, W2r, b2r, xr2, N, 128, 512);
    score2_kernel<<<(E + 3) / 4, 256, 0, stream>>>(xl2, xr2, ssrc, sdst, att2, sc2, E);
    agg2_kernel<<<(N + 3) / 4, 256, 0, stream>>>(xl2, sc2, row_start, ssrc, bias2, h2, N);

    // --- heads ---
    heads_kernel<<<(N + 3) / 4, 256, 0, stream>>>(h2, Wa, ba, Wrc, brc, out, N);
}

// Round 6
// 471.275 us; speedup vs baseline: 1.8487x; 1.8487x over previous
//
#include <hip/hip_runtime.h>
#include <hip/hip_bf16.h>

#define N_NODES 20000
#define N_EDGES 320000
#define IN_DIM 256
#define HID 128
#define HEADS 4
#define MPAD 20096   // 157 * 128

typedef unsigned short u16;
typedef __attribute__((ext_vector_type(8))) short bf16x8;
typedef __attribute__((ext_vector_type(4))) float f32x4;
typedef __attribute__((address_space(1))) void g_void;
typedef __attribute__((address_space(3))) void l_void;

__device__ __forceinline__ float bfu(unsigned int u) {
    union { unsigned int i; float f; } c; c.i = u << 16; return c.f;
}
__device__ __forceinline__ u16 f2bf(float f) {
    union { float f; unsigned int i; } c; c.f = f;
    return (u16)((c.i + 0x7FFF + ((c.i >> 16) & 1)) >> 16);   // RNE
}

// ---------------------------------------------------------------------------
// CSR build: histogram -> scan -> scatter(eid) -> per-segment sort -> fill
// Deterministic: segments are sorted by original edge index every call.
// ---------------------------------------------------------------------------
__global__ void hist_kernel(const int* __restrict__ dst, int* __restrict__ deg, int E) {
    int i = blockIdx.x * blockDim.x + threadIdx.x;
    if (i < E) atomicAdd(&deg[dst[i]], 1);
}

__global__ void scan_kernel(const int* __restrict__ deg, int* __restrict__ row_start,
                            int* __restrict__ cursor, int n) {
    __shared__ int partial[256];
    int t = threadIdx.x;
    int chunk = (n + 255) / 256;
    int begin = t * chunk;
    int end = min(begin + chunk, n);
    int s = 0;
    for (int i = begin; i < end; ++i) s += deg[i];
    partial[t] = s;
    __syncthreads();
    for (int off = 1; off < 256; off <<= 1) {
        int v = (t >= off) ? partial[t - off] : 0;
        __syncthreads();
        partial[t] += v;
        __syncthreads();
    }
    int run = (t == 0) ? 0 : partial[t - 1];
    for (int i = begin; i < end; ++i) {
        row_start[i] = run;
        cursor[i] = run;
        run += deg[i];
    }
    if (t == 255) row_start[n] = run;
}

__global__ void scatter_kernel(const int* __restrict__ dst, int* __restrict__ cursor,
                               int* __restrict__ seid, int E) {
    int i = blockIdx.x * blockDim.x + threadIdx.x;
    if (i < E) {
        int pos = atomicAdd(&cursor[dst[i]], 1);
        seid[pos] = i;
    }
}

__global__ void sort_kernel(const int* __restrict__ row_start, int* __restrict__ seid, int n) {
    int node = blockIdx.x * blockDim.x + threadIdx.x;
    if (node >= n) return;
    int beg = row_start[node], end = row_start[node + 1];
    for (int i = beg + 1; i < end; ++i) {
        int v = seid[i];
        int j = i - 1;
        while (j >= beg && seid[j] > v) { seid[j + 1] = seid[j]; --j; }
        seid[j + 1] = v;
    }
}

__global__ void fill_kernel(const int* __restrict__ seid, const int* __restrict__ src,
                            const int* __restrict__ dst, int* __restrict__ ssrc,
                            int* __restrict__ sdst, int E) {
    int i = blockIdx.x * blockDim.x + threadIdx.x;
    if (i < E) {
        int e = seid[i];
        ssrc[i] = src[e];
        sdst[i] = dst[e];
    }
}

// ---------------------------------------------------------------------------
// cast x (fp32 [20000][256]) -> bf16 [MPAD][256], pad rows zeroed
// ---------------------------------------------------------------------------
__global__ void cast_x_kernel(const float* __restrict__ x, u16* __restrict__ xb) {
    int i = blockIdx.x * blockDim.x + threadIdx.x;     // quad id
    const int nq = MPAD * IN_DIM / 4;
    if (i >= nq) return;
    int elem = i * 4;
    uint2 u;
    if (elem < N_NODES * IN_DIM) {
        float4 v = ((const float4*)x)[i];
        u.x = (unsigned)f2bf(v.x) | ((unsigned)f2bf(v.y) << 16);
        u.y = (unsigned)f2bf(v.z) | ((unsigned)f2bf(v.w) << 16);
    } else {
        u.x = 0u; u.y = 0u;
    }
    *(uint2*)(xb + elem) = u;
}

// ---------------------------------------------------------------------------
// transpose+cast: W fp32 [K][N] -> out bf16 [N][K]
// ---------------------------------------------------------------------------
__global__ __launch_bounds__(256) void transpose_cast_kernel(
    const float* __restrict__ W, u16* __restrict__ out, int K, int N) {
    __shared__ float t[32][33];
    int bx = blockIdx.x * 32;   // n base
    int by = blockIdx.y * 32;   // k base
    int tx = threadIdx.x, ty = threadIdx.y;
    #pragma unroll
    for (int j = 0; j < 32; j += 8)
        t[ty + j][tx] = W[(size_t)(by + ty + j) * N + bx + tx];
    __syncthreads();
    #pragma unroll
    for (int j = 0; j < 32; j += 8)
        out[(size_t)(bx + ty + j) * K + by + tx] = f2bf(t[tx][ty + j]);
}

// ---------------------------------------------------------------------------
// concat biases (fp32)
// ---------------------------------------------------------------------------
__global__ void prep_bias_kernel(const float* b1l, const float* b1r,
                                 const float* b2l, const float* b2r,
                                 float* bc1, float* bc2) {
    int t = threadIdx.x;   // one block of 1024
    if (t < 512) bc1[t] = b1l[t];
    else bc1[t] = b1r[t - 512];
    if (t < 128) bc2[t] = b2l[t];
    else if (t < 256) bc2[t] = b2r[t - 128];
}

// ---------------------------------------------------------------------------
// bf16 MFMA GEMM: C[Mrows][N] = A[MPAD][K] @ BT[N][K]^T + bias, bf16 out
// tile 128x128, BK=32, 256 threads (4 waves 2x2), 4x4 16x16 frags per wave
// LDS k-slot XOR swizzle: slot = kgroup ^ ((row>>1)&3)  (both sides)
// ---------------------------------------------------------------------------
__global__ __launch_bounds__(256) void gemm_bf16_kernel(
    const u16* __restrict__ A, const u16* __restrict__ BT,
    const float* __restrict__ bias, u16* __restrict__ C,
    int K, int Mrows, int N) {
    __shared__ u16 As[4096];
    __shared__ u16 Bs[4096];
    const int tid = threadIdx.x;
    const int lane = tid & 63;
    const int wid = tid >> 6;
    const int wr = wid >> 1, wc = wid & 1;
    const int brow = blockIdx.y * 128, bcol = blockIdx.x * 128;

    const int srow = tid >> 2;
    const int skk = (((tid & 3) ^ ((tid >> 3) & 3))) * 8;
    const u16* ga0 = A + (size_t)(brow + srow) * K + skk;
    const u16* ga1 = A + (size_t)(brow + 64 + srow) * K + skk;
    const u16* gb0 = BT + (size_t)(bcol + srow) * K + skk;
    const u16* gb1 = BT + (size_t)(bcol + 64 + srow) * K + skk;
    u16* lA0 = As + tid * 8;
    u16* lA1 = As + 2048 + tid * 8;
    u16* lB0 = Bs + tid * 8;
    u16* lB1 = Bs + 2048 + tid * 8;

    const int fr = lane & 15;
    const int fg = lane >> 4;
    const int fslot = (fg ^ ((fr >> 1) & 3)) * 8;
    const u16* ra = As + (wr * 64 + fr) * 32 + fslot;
    const u16* rb = Bs + (wc * 64 + fr) * 32 + fslot;

    f32x4 acc[4][4];
    #pragma unroll
    for (int m = 0; m < 4; ++m)
        #pragma unroll
        for (int n = 0; n < 4; ++n)
            acc[m][n] = (f32x4){0.f, 0.f, 0.f, 0.f};

    for (int k0 = 0; k0 < K; k0 += 32) {
        __builtin_amdgcn_global_load_lds((const g_void*)(ga0 + k0), (l_void*)lA0, 16, 0, 0);
        __builtin_amdgcn_global_load_lds((const g_void*)(ga1 + k0), (l_void*)lA1, 16, 0, 0);
        __builtin_amdgcn_global_load_lds((const g_void*)(gb0 + k0), (l_void*)lB0, 16, 0, 0);
        __builtin_amdgcn_global_load_lds((const g_void*)(gb1 + k0), (l_void*)lB1, 16, 0, 0);
        __syncthreads();
        bf16x8 av[4], bv[4];
        #pragma unroll
        for (int m = 0; m < 4; ++m) av[m] = *(const bf16x8*)(ra + m * 512);
        #pragma unroll
        for (int n = 0; n < 4; ++n) bv[n] = *(const bf16x8*)(rb + n * 512);
        #pragma unroll
        for (int m = 0; m < 4; ++m)
            #pragma unroll
            for (int n = 0; n < 4; ++n)
                acc[m][n] = __builtin_amdgcn_mfma_f32_16x16x32_bf16(av[m], bv[n], acc[m][n], 0, 0, 0);
        __syncthreads();
    }

    // C/D layout (m89-verified): col = lane&15, row = (lane>>4)*4 + reg
    const int col0 = bcol + wc * 64 + fr;
    const int row0 = brow + wr * 64 + fg * 4;
    #pragma unroll
    for (int n = 0; n < 4; ++n) {
        const int col = col0 + n * 16;
        const float bv2 = bias[col];
        #pragma unroll
        for (int m = 0; m < 4; ++m) {
            const int r0 = row0 + m * 16;
            #pragma unroll
            for (int j = 0; j < 4; ++j) {
                int r = r0 + j;
                if (r < Mrows) C[(size_t)r * N + col] = f2bf(acc[m][n][j] + bv2);
            }
        }
    }
}

// ---------------------------------------------------------------------------
// Layer-1 edge scores (bf16 in): xlr [MPAD][1024]; xl = +0, xr = +512
// ---------------------------------------------------------------------------
__global__ __launch_bounds__(256) void score1_kernel(
    const u16* __restrict__ xlr, const int* __restrict__ ssrc,
    const int* __restrict__ sdst, const float* __restrict__ att1,
    float* __restrict__ score, int E) {
    int e = blockIdx.x * 4 + (threadIdx.x >> 6);
    int lane = threadIdx.x & 63;
    if (e >= E) return;
    int s = ssrc[e], d = sdst[e];
    uint4 lv = *(const uint4*)(xlr + (size_t)s * 1024 + lane * 8);
    uint4 rv = *(const uint4*)(xlr + (size_t)d * 1024 + 512 + lane * 8);
    float4 a0 = ((const float4*)att1)[lane * 2];
    float4 a1 = ((const float4*)att1)[lane * 2 + 1];
    float l[8] = { bfu(lv.x & 0xffff), bfu(lv.x >> 16), bfu(lv.y & 0xffff), bfu(lv.y >> 16),
                   bfu(lv.z & 0xffff), bfu(lv.z >> 16), bfu(lv.w & 0xffff), bfu(lv.w >> 16) };
    float r[8] = { bfu(rv.x & 0xffff), bfu(rv.x >> 16), bfu(rv.y & 0xffff), bfu(rv.y >> 16),
                   bfu(rv.z & 0xffff), bfu(rv.z >> 16), bfu(rv.w & 0xffff), bfu(rv.w >> 16) };
    float w[8] = { a0.x, a0.y, a0.z, a0.w, a1.x, a1.y, a1.z, a1.w };
    float acc = 0.f;
    #pragma unroll
    for (int j = 0; j < 8; ++j) {
        float v = l[j] + r[j];
        v = v > 0.f ? v : 0.2f * v;
        acc += v * w[j];
    }
    acc += __shfl_xor(acc, 1);
    acc += __shfl_xor(acc, 2);
    acc += __shfl_xor(acc, 4);
    acc += __shfl_xor(acc, 8);
    if ((lane & 15) == 0) score[(size_t)e * 4 + (lane >> 4)] = acc;
}

// ---------------------------------------------------------------------------
// Layer-1 aggregation: block per node, wave per head -> h1 bf16 [MPAD][512]
// ---------------------------------------------------------------------------
__global__ __launch_bounds__(256) void agg1_kernel(
    const u16* __restrict__ xlr, const float* __restrict__ score,
    const int* __restrict__ row_start, const int* __restrict__ ssrc,
    const float* __restrict__ bias1, u16* __restrict__ h1, int n) {
    int node = blockIdx.x;
    int wid = threadIdx.x >> 6;
    int lane = threadIdx.x & 63;
    int beg = row_start[node], end = row_start[node + 1];
    float m = -3.402823466e38f;
    for (int p = beg + lane; p < end; p += 64)
        m = fmaxf(m, score[(size_t)p * 4 + wid]);
    #pragma unroll
    for (int off = 1; off < 64; off <<= 1) m = fmaxf(m, __shfl_xor(m, off));
    float ssum = 0.f;
    for (int p = beg + lane; p < end; p += 64)
        ssum += __expf(score[(size_t)p * 4 + wid] - m);
    #pragma unroll
    for (int off = 1; off < 64; off <<= 1) ssum += __shfl_xor(ssum, off);
    float inv = 1.f / (ssum + 1e-16f);
    float acc0 = 0.f, acc1 = 0.f;
    for (int p = beg; p < end; ++p) {
        float a = __expf(score[(size_t)p * 4 + wid] - m) * inv;
        const u16* px = xlr + (size_t)ssrc[p] * 1024 + wid * 128;
        acc0 += a * bfu(px[lane]);
        acc1 += a * bfu(px[lane + 64]);
    }
    int c = wid * 128 + lane;
    float v0 = acc0 + bias1[c];
    float v1 = acc1 + bias1[c + 64];
    v0 = v0 > 0.f ? v0 : __expf(v0) - 1.f;   // ELU
    v1 = v1 > 0.f ? v1 : __expf(v1) - 1.f;
    h1[(size_t)node * 512 + c] = f2bf(v0);
    h1[(size_t)node * 512 + c + 64] = f2bf(v1);
}

// ---------------------------------------------------------------------------
// Layer-2 edge scores (bf16 in): xlr2 [MPAD][256]; xl2 = +0, xr2 = +128
// ---------------------------------------------------------------------------
__global__ __launch_bounds__(256) void score2_kernel(
    const u16* __restrict__ xlr2, const int* __restrict__ ssrc,
    const int* __restrict__ sdst, const float* __restrict__ att2,
    float* __restrict__ score2, int E) {
    int e = blockIdx.x * 4 + (threadIdx.x >> 6);
    int lane = threadIdx.x & 63;
    if (e >= E) return;
    int s = ssrc[e], d = sdst[e];
    unsigned int l = *(const unsigned int*)(xlr2 + (size_t)s * 256 + lane * 2);
    unsigned int r = *(const unsigned int*)(xlr2 + (size_t)d * 256 + 128 + lane * 2);
    float2 w = ((const float2*)att2)[lane];
    float ax = bfu(l & 0xffff) + bfu(r & 0xffff); ax = ax > 0.f ? ax : 0.2f * ax;
    float ay = bfu(l >> 16) + bfu(r >> 16);       ay = ay > 0.f ? ay : 0.2f * ay;
    float acc = ax * w.x + ay * w.y;
    #pragma unroll
    for (int off = 1; off < 64; off <<= 1) acc += __shfl_xor(acc, off);
    if (lane == 0) score2[e] = acc;
}

// ---------------------------------------------------------------------------
// Layer-2 aggregation: wave per node -> h2 fp32 [N][128]
// ---------------------------------------------------------------------------
__global__ __launch_bounds__(256) void agg2_kernel(
    const u16* __restrict__ xlr2, const float* __restrict__ score2,
    const int* __restrict__ row_start, const int* __restrict__ ssrc,
    const float* __restrict__ bias2, float* __restrict__ h2, int n) {
    int node = blockIdx.x * 4 + (threadIdx.x >> 6);
    int lane = threadIdx.x & 63;
    if (node >= n) return;
    int beg = row_start[node], end = row_start[node + 1];
    float m = -3.402823466e38f;
    for (int p = beg + lane; p < end; p += 64) m = fmaxf(m, score2[p]);
    #pragma unroll
    for (int off = 1; off < 64; off <<= 1) m = fmaxf(m, __shfl_xor(m, off));
    float ssum = 0.f;
    for (int p = beg + lane; p < end; p += 64) ssum += __expf(score2[p] - m);
    #pragma unroll
    for (int off = 1; off < 64; off <<= 1) ssum += __shfl_xor(ssum, off);
    float inv = 1.f / (ssum + 1e-16f);
    float acc0 = 0.f, acc1 = 0.f;
    for (int p = beg; p < end; ++p) {
        float a = __expf(score2[p] - m) * inv;
        const u16* px = xlr2 + (size_t)ssrc[p] * 256;
        acc0 += a * bfu(px[lane]);
        acc1 += a * bfu(px[lane + 64]);
    }
    h2[(size_t)node * 128 + lane] = acc0 + bias2[lane];
    h2[(size_t)node * 128 + lane + 64] = acc1 + bias2[lane + 64];
}

// ---------------------------------------------------------------------------
// Heads: wave per node, two 128-dots + sigmoid
// ---------------------------------------------------------------------------
__global__ __launch_bounds__(256) void heads_kernel(
    const float* __restrict__ h2, const float* __restrict__ Wa,
    const float* __restrict__ ba, const float* __restrict__ Wrc,
    const float* __restrict__ brc, float* __restrict__ out, int n) {
    int node = blockIdx.x * 4 + (threadIdx.x >> 6);
    int lane = threadIdx.x & 63;
    if (node >= n) return;
    const float* p = h2 + (size_t)node * 128;
    float v0 = p[lane], v1 = p[lane + 64];
    float a = v0 * Wa[lane] + v1 * Wa[lane + 64];
    float r = v0 * Wrc[lane] + v1 * Wrc[lane + 64];
    #pragma unroll
    for (int off = 1; off < 64; off <<= 1) {
        a += __shfl_xor(a, off);
        r += __shfl_xor(r, off);
    }
    if (lane == 0) {
        out[node]     = 1.f / (1.f + __expf(-(a + ba[0])));
        out[n + node] = 1.f / (1.f + __expf(-(r + brc[0])));
    }
}

// ---------------------------------------------------------------------------
extern "C" void kernel_launch(void* const* d_in, const int* in_sizes, int n_in,
                              void* d_out, int out_size, void* d_ws, size_t ws_size,
                              hipStream_t stream) {
    const float* x    = (const float*)d_in[0];
    const int* ei     = (const int*)d_in[1];
    const float* W1l  = (const float*)d_in[2];
    const float* b1l  = (const float*)d_in[3];
    const float* W1r  = (const float*)d_in[4];
    const float* b1r  = (const float*)d_in[5];
    const float* att1 = (const float*)d_in[6];
    const float* bias1= (const float*)d_in[7];
    const float* W2l  = (const float*)d_in[8];
    const float* b2l  = (const float*)d_in[9];
    const float* W2r  = (const float*)d_in[10];
    const float* b2r  = (const float*)d_in[11];
    const float* att2 = (const float*)d_in[12];
    const float* bias2= (const float*)d_in[13];
    const float* Wa   = (const float*)d_in[14];
    const float* ba   = (const float*)d_in[15];
    const float* Wrc  = (const float*)d_in[16];
    const float* brc  = (const float*)d_in[17];
    float* out = (float*)d_out;

    const int N = N_NODES, E = N_EDGES;
    const int* src = ei;
    const int* dst = ei + E;

    char* ws = (char*)d_ws;
    // xlr1: [MPAD][1024] bf16 = 41,156,608 B @ 0 ; h2 fp32 reuses @0 after agg1
    u16*   xlr1 = (u16*)ws;
    float* h2   = (float*)ws;
    // h1b: [MPAD][512] bf16 @ 41,156,608 (20,578,304 B)
    u16*   h1b  = (u16*)(ws + 41156608);
    // xb: [MPAD][256] bf16 @ 61,734,912 (10,289,152 B); xlr2 reuses after gemm1
    u16*   xb   = (u16*)(ws + 61734912);
    u16*   xlr2 = (u16*)(ws + 61734912);
    // sc1 @ 72,024,064 (5,120,000); sc2 @ 77,144,064 (1,280,000)
    float* sc1  = (float*)(ws + 72024064);
    float* sc2  = (float*)(ws + 77144064);
    // BT1 [1024][256] bf16 @ 78,424,064 (524,288); BT2 [256][512] @ 78,948,352 (262,144)
    u16*   BT1  = (u16*)(ws + 78424064);
    u16*   BT2  = (u16*)(ws + 78948352);
    float* bc1  = (float*)(ws + 79210496);            // 4096
    float* bc2  = (float*)(ws + 79214592);            // 1024
    int* deg       = (int*)(ws + 79215616);           // 80,000
    int* row_start = (int*)(ws + 79296000);           // 80,004
    int* cursor    = (int*)(ws + 79376128);           // 80,000
    int* ssrc      = (int*)(ws + 79456128);           // 1,280,000
    int* sdst      = (int*)(ws + 80736128);           // 1,280,000
    int* seid      = (int*)(ws + 82016128);           // 1,280,000
    // end ~83.3 MB (proven-available: 89.8 MB in round 3)

    // --- CSR build (deterministic) ---
    hipMemsetAsync(deg, 0, N * sizeof(int), stream);
    hist_kernel<<<(E + 255) / 256, 256, 0, stream>>>(dst, deg, E);
    scan_kernel<<<1, 256, 0, stream>>>(deg, row_start, cursor, N);
    scatter_kernel<<<(E + 255) / 256, 256, 0, stream>>>(dst, cursor, seid, E);
    sort_kernel<<<(N + 255) / 256, 256, 0, stream>>>(row_start, seid, N);
    fill_kernel<<<(E + 255) / 256, 256, 0, stream>>>(seid, src, dst, ssrc, sdst, E);

    // --- casts / weight prep ---
    cast_x_kernel<<<(MPAD * IN_DIM / 4 + 255) / 256, 256, 0, stream>>>(x, xb);
    dim3 tb(32, 8);
    transpose_cast_kernel<<<dim3(16, 8), tb, 0, stream>>>(W1l, BT1, 256, 512);
    transpose_cast_kernel<<<dim3(16, 8), tb, 0, stream>>>(W1r, BT1 + 512 * 256, 256, 512);
    transpose_cast_kernel<<<dim3(4, 16), tb, 0, stream>>>(W2l, BT2, 512, 128);
    transpose_cast_kernel<<<dim3(4, 16), tb, 0, stream>>>(W2r, BT2 + 128 * 512, 512, 128);
    prep_bias_kernel<<<1, 1024, 0, stream>>>(b1l, b1r, b2l, b2r, bc1, bc2);

    // --- layer 1: fused GEMM (xl|xr), then edge softmax+aggregate ---
    gemm_bf16_kernel<<<dim3(8, 157), 256, 0, stream>>>(xb, BT1, bc1, xlr1, 256, N, 1024);
    score1_kernel<<<(E + 3) / 4, 256, 0, stream>>>(xlr1, ssrc, sdst, att1, sc1, E);
    agg1_kernel<<<N, 256, 0, stream>>>(xlr1, sc1, row_start, ssrc, bias1, h1b, N);

    // --- layer 2 ---
    gemm_bf16_kernel<<<dim3(2, 157), 256, 0, stream>>>(h1b, BT2, bc2, xlr2, 512, N, 256);
    score2_kernel<<<(E + 3) / 4, 256, 0, stream>>>(xlr2, ssrc, sdst, att2, sc2, E);
    agg2_kernel<<<(N + 3) / 4, 256, 0, stream>>>(xlr2, sc2, row_start, ssrc, bias2, h2, N);

    // --- heads ---
    heads_kernel<<<(N + 3) / 4, 256, 0, stream>>>(h2, Wa, ba, Wrc, brc, out, N);
}

// Round 7
// 333.373 us; speedup vs baseline: 2.6135x; 1.4137x over previous
//
#include <hip/hip_runtime.h>
#include <hip/hip_bf16.h>

#define N_NODES 20000
#define N_EDGES 320000
#define IN_DIM 256
#define HID 128
#define HEADS 4
#define MPAD 20096   // 157 * 128

typedef unsigned short u16;
typedef __attribute__((ext_vector_type(8))) short bf16x8;
typedef __attribute__((ext_vector_type(4))) float f32x4;
typedef __attribute__((address_space(1))) void g_void;
typedef __attribute__((address_space(3))) void l_void;

__device__ __forceinline__ float bfu(unsigned int u) {
    union { unsigned int i; float f; } c; c.i = u << 16; return c.f;
}
__device__ __forceinline__ u16 f2bf(float f) {
    union { float f; unsigned int i; } c; c.f = f;
    return (u16)((c.i + 0x7FFF + ((c.i >> 16) & 1)) >> 16);   // RNE
}

// ---------------------------------------------------------------------------
// CSR build: histogram -> scan -> scatter(eid) -> per-segment sort -> fill
// Deterministic: segments sorted by original edge index every call.
// ---------------------------------------------------------------------------
__global__ void hist_kernel(const int* __restrict__ dst, int* __restrict__ deg, int E) {
    int i = blockIdx.x * blockDim.x + threadIdx.x;
    if (i < E) atomicAdd(&deg[dst[i]], 1);
}

__global__ void scan_kernel(const int* __restrict__ deg, int* __restrict__ row_start,
                            int* __restrict__ cursor, int n) {
    __shared__ int partial[256];
    int t = threadIdx.x;
    int chunk = (n + 255) / 256;
    int begin = t * chunk;
    int end = min(begin + chunk, n);
    int s = 0;
    for (int i = begin; i < end; ++i) s += deg[i];
    partial[t] = s;
    __syncthreads();
    for (int off = 1; off < 256; off <<= 1) {
        int v = (t >= off) ? partial[t - off] : 0;
        __syncthreads();
        partial[t] += v;
        __syncthreads();
    }
    int run = (t == 0) ? 0 : partial[t - 1];
    for (int i = begin; i < end; ++i) {
        row_start[i] = run;
        cursor[i] = run;
        run += deg[i];
    }
    if (t == 255) row_start[n] = run;
}

__global__ void scatter_kernel(const int* __restrict__ dst, int* __restrict__ cursor,
                               int* __restrict__ seid, int E) {
    int i = blockIdx.x * blockDim.x + threadIdx.x;
    if (i < E) {
        int pos = atomicAdd(&cursor[dst[i]], 1);
        seid[pos] = i;
    }
}

__global__ void sort_kernel(const int* __restrict__ row_start, int* __restrict__ seid, int n) {
    int node = blockIdx.x * blockDim.x + threadIdx.x;
    if (node >= n) return;
    int beg = row_start[node], end = row_start[node + 1];
    for (int i = beg + 1; i < end; ++i) {
        int v = seid[i];
        int j = i - 1;
        while (j >= beg && seid[j] > v) { seid[j + 1] = seid[j]; --j; }
        seid[j + 1] = v;
    }
}

__global__ void fill_kernel(const int* __restrict__ seid, const int* __restrict__ src,
                            int* __restrict__ ssrc, int E) {
    int i = blockIdx.x * blockDim.x + threadIdx.x;
    if (i < E) ssrc[i] = src[seid[i]];
}

// ---------------------------------------------------------------------------
// cast x (fp32 [20000][256]) -> bf16 [MPAD][256], pad rows zeroed
// ---------------------------------------------------------------------------
__global__ void cast_x_kernel(const float* __restrict__ x, u16* __restrict__ xb) {
    int i = blockIdx.x * blockDim.x + threadIdx.x;     // quad id
    const int nq = MPAD * IN_DIM / 4;
    if (i >= nq) return;
    int elem = i * 4;
    uint2 u;
    if (elem < N_NODES * IN_DIM) {
        float4 v = ((const float4*)x)[i];
        u.x = (unsigned)f2bf(v.x) | ((unsigned)f2bf(v.y) << 16);
        u.y = (unsigned)f2bf(v.z) | ((unsigned)f2bf(v.w) << 16);
    } else {
        u.x = 0u; u.y = 0u;
    }
    *(uint2*)(xb + elem) = u;
}

// ---------------------------------------------------------------------------
// transpose+cast: W fp32 [K][N] -> out bf16 [N][K]
// ---------------------------------------------------------------------------
__global__ __launch_bounds__(256) void transpose_cast_kernel(
    const float* __restrict__ W, u16* __restrict__ out, int K, int N) {
    __shared__ float t[32][33];
    int bx = blockIdx.x * 32;   // n base
    int by = blockIdx.y * 32;   // k base
    int tx = threadIdx.x, ty = threadIdx.y;
    #pragma unroll
    for (int j = 0; j < 32; j += 8)
        t[ty + j][tx] = W[(size_t)(by + ty + j) * N + bx + tx];
    __syncthreads();
    #pragma unroll
    for (int j = 0; j < 32; j += 8)
        out[(size_t)(bx + ty + j) * K + by + tx] = f2bf(t[tx][ty + j]);
}

// ---------------------------------------------------------------------------
// concat biases (fp32)
// ---------------------------------------------------------------------------
__global__ void prep_bias_kernel(const float* b1l, const float* b1r,
                                 const float* b2l, const float* b2r,
                                 float* bc1, float* bc2) {
    int t = threadIdx.x;   // one block of 1024
    if (t < 512) bc1[t] = b1l[t];
    else bc1[t] = b1r[t - 512];
    if (t < 128) bc2[t] = b2l[t];
    else if (t < 256) bc2[t] = b2r[t - 128];
}

// ---------------------------------------------------------------------------
// bf16 MFMA GEMM: C[Mrows][N] = A[MPAD][K] @ BT[N][K]^T + bias, bf16 out
// tile 128x128, BK=32, 256 threads (4 waves 2x2), 4x4 16x16 frags per wave
// ---------------------------------------------------------------------------
__global__ __launch_bounds__(256) void gemm_bf16_kernel(
    const u16* __restrict__ A, const u16* __restrict__ BT,
    const float* __restrict__ bias, u16* __restrict__ C,
    int K, int Mrows, int N) {
    __shared__ u16 As[4096];
    __shared__ u16 Bs[4096];
    const int tid = threadIdx.x;
    const int lane = tid & 63;
    const int wid = tid >> 6;
    const int wr = wid >> 1, wc = wid & 1;
    const int brow = blockIdx.y * 128, bcol = blockIdx.x * 128;

    const int srow = tid >> 2;
    const int skk = (((tid & 3) ^ ((tid >> 3) & 3))) * 8;
    const u16* ga0 = A + (size_t)(brow + srow) * K + skk;
    const u16* ga1 = A + (size_t)(brow + 64 + srow) * K + skk;
    const u16* gb0 = BT + (size_t)(bcol + srow) * K + skk;
    const u16* gb1 = BT + (size_t)(bcol + 64 + srow) * K + skk;
    u16* lA0 = As + tid * 8;
    u16* lA1 = As + 2048 + tid * 8;
    u16* lB0 = Bs + tid * 8;
    u16* lB1 = Bs + 2048 + tid * 8;

    const int fr = lane & 15;
    const int fg = lane >> 4;
    const int fslot = (fg ^ ((fr >> 1) & 3)) * 8;
    const u16* ra = As + (wr * 64 + fr) * 32 + fslot;
    const u16* rb = Bs + (wc * 64 + fr) * 32 + fslot;

    f32x4 acc[4][4];
    #pragma unroll
    for (int m = 0; m < 4; ++m)
        #pragma unroll
        for (int n = 0; n < 4; ++n)
            acc[m][n] = (f32x4){0.f, 0.f, 0.f, 0.f};

    for (int k0 = 0; k0 < K; k0 += 32) {
        __builtin_amdgcn_global_load_lds((const g_void*)(ga0 + k0), (l_void*)lA0, 16, 0, 0);
        __builtin_amdgcn_global_load_lds((const g_void*)(ga1 + k0), (l_void*)lA1, 16, 0, 0);
        __builtin_amdgcn_global_load_lds((const g_void*)(gb0 + k0), (l_void*)lB0, 16, 0, 0);
        __builtin_amdgcn_global_load_lds((const g_void*)(gb1 + k0), (l_void*)lB1, 16, 0, 0);
        __syncthreads();
        bf16x8 av[4], bv[4];
        #pragma unroll
        for (int m = 0; m < 4; ++m) av[m] = *(const bf16x8*)(ra + m * 512);
        #pragma unroll
        for (int n = 0; n < 4; ++n) bv[n] = *(const bf16x8*)(rb + n * 512);
        #pragma unroll
        for (int m = 0; m < 4; ++m)
            #pragma unroll
            for (int n = 0; n < 4; ++n)
                acc[m][n] = __builtin_amdgcn_mfma_f32_16x16x32_bf16(av[m], bv[n], acc[m][n], 0, 0, 0);
        __syncthreads();
    }

    const int col0 = bcol + wc * 64 + fr;
    const int row0 = brow + wr * 64 + fg * 4;
    #pragma unroll
    for (int n = 0; n < 4; ++n) {
        const int col = col0 + n * 16;
        const float bv2 = bias[col];
        #pragma unroll
        for (int m = 0; m < 4; ++m) {
            const int r0 = row0 + m * 16;
            #pragma unroll
            for (int j = 0; j < 4; ++j) {
                int r = r0 + j;
                if (r < Mrows) C[(size_t)r * N + col] = f2bf(acc[m][n][j] + bv2);
            }
        }
    }
}

// ---------------------------------------------------------------------------
// fused layer-1 edge phase: one wave per node, online softmax.
// xlr [MPAD][1024] (xl|xr). Lane covers xl channels lane*8..lane*8+7,
// head = lane>>4 (128 ch per head = 16 lanes). Per edge: one bf16x8 gather
// of xl[src], score via per-head 16-lane reduce, flash-style m/l/acc update.
// Epilogue: /denom, +bias1, ELU, bf16x8 store -> h1.
// ---------------------------------------------------------------------------
__global__ __launch_bounds__(256) void fused1_kernel(
    const u16* __restrict__ xlr, const int* __restrict__ row_start,
    const int* __restrict__ ssrc, const float* __restrict__ att1,
    const float* __restrict__ bias1, u16* __restrict__ h1, int n) {
    int node = blockIdx.x * 4 + (threadIdx.x >> 6);
    int lane = threadIdx.x & 63;
    if (node >= n) return;

    // xr row (loaded once per node) and attention weights
    bf16x8 xrv = *(const bf16x8*)(xlr + (size_t)node * 1024 + 512 + lane * 8);
    float xrf[8], wa[8];
    #pragma unroll
    for (int j = 0; j < 8; ++j) xrf[j] = bfu((u16)xrv[j]);
    float4 w0 = ((const float4*)att1)[lane * 2];
    float4 w1 = ((const float4*)att1)[lane * 2 + 1];
    wa[0] = w0.x; wa[1] = w0.y; wa[2] = w0.z; wa[3] = w0.w;
    wa[4] = w1.x; wa[5] = w1.y; wa[6] = w1.z; wa[7] = w1.w;

    int beg = row_start[node], end = row_start[node + 1];
    float m = -3.402823466e38f, l = 0.f;
    float acc[8] = {0.f, 0.f, 0.f, 0.f, 0.f, 0.f, 0.f, 0.f};

    bf16x8 xv = {};
    if (beg < end) xv = *(const bf16x8*)(xlr + (size_t)ssrc[beg] * 1024 + lane * 8);
    for (int p = beg; p < end; ++p) {
        bf16x8 cur = xv;
        if (p + 1 < end)   // prefetch next source row
            xv = *(const bf16x8*)(xlr + (size_t)ssrc[p + 1] * 1024 + lane * 8);
        float xf[8];
        #pragma unroll
        for (int j = 0; j < 8; ++j) xf[j] = bfu((u16)cur[j]);
        float sc = 0.f;
        #pragma unroll
        for (int j = 0; j < 8; ++j) {
            float v = xf[j] + xrf[j];
            v = v > 0.f ? v : 0.2f * v;
            sc += v * wa[j];
        }
        sc += __shfl_xor(sc, 1);
        sc += __shfl_xor(sc, 2);
        sc += __shfl_xor(sc, 4);
        sc += __shfl_xor(sc, 8);       // per-head score, all 16 lanes have it
        float mn = fmaxf(m, sc);
        float corr = __expf(m - mn);   // first iter: exp(-huge) = 0
        float pv = __expf(sc - mn);
        l = l * corr + pv;
        #pragma unroll
        for (int j = 0; j < 8; ++j) acc[j] = acc[j] * corr + pv * xf[j];
        m = mn;
    }

    float inv = 1.f / (l + 1e-16f);
    float4 b0 = ((const float4*)bias1)[lane * 2];
    float4 b1 = ((const float4*)bias1)[lane * 2 + 1];
    float bb[8] = {b0.x, b0.y, b0.z, b0.w, b1.x, b1.y, b1.z, b1.w};
    bf16x8 outv;
    #pragma unroll
    for (int j = 0; j < 8; ++j) {
        float v = acc[j] * inv + bb[j];
        v = v > 0.f ? v : __expf(v) - 1.f;   // ELU
        outv[j] = (short)f2bf(v);
    }
    *(bf16x8*)(h1 + (size_t)node * 512 + lane * 8) = outv;
}

// ---------------------------------------------------------------------------
// fused layer-2 edge phase + heads: one wave per node, online softmax,
// then anomaly/root-cause dots + sigmoid. xlr2 [MPAD][256] (xl2|xr2),
// lane covers channels lane*2, lane*2+1 (1 head, full-wave reduce).
// ---------------------------------------------------------------------------
__global__ __launch_bounds__(256) void fused2_kernel(
    const u16* __restrict__ xlr2, const int* __restrict__ row_start,
    const int* __restrict__ ssrc, const float* __restrict__ att2,
    const float* __restrict__ bias2, const float* __restrict__ Wa,
    const float* __restrict__ ba, const float* __restrict__ Wrc,
    const float* __restrict__ brc, float* __restrict__ out, int n) {
    int node = blockIdx.x * 4 + (threadIdx.x >> 6);
    int lane = threadIdx.x & 63;
    if (node >= n) return;

    unsigned int xr = *(const unsigned int*)(xlr2 + (size_t)node * 256 + 128 + lane * 2);
    float xr0 = bfu(xr & 0xffff), xr1 = bfu(xr >> 16);
    float2 w = ((const float2*)att2)[lane];

    int beg = row_start[node], end = row_start[node + 1];
    float m = -3.402823466e38f, l = 0.f;
    float acc0 = 0.f, acc1 = 0.f;

    unsigned int xv = 0;
    if (beg < end) xv = *(const unsigned int*)(xlr2 + (size_t)ssrc[beg] * 256 + lane * 2);
    for (int p = beg; p < end; ++p) {
        unsigned int cur = xv;
        if (p + 1 < end)
            xv = *(const unsigned int*)(xlr2 + (size_t)ssrc[p + 1] * 256 + lane * 2);
        float x0 = bfu(cur & 0xffff), x1 = bfu(cur >> 16);
        float v0 = x0 + xr0; v0 = v0 > 0.f ? v0 : 0.2f * v0;
        float v1 = x1 + xr1; v1 = v1 > 0.f ? v1 : 0.2f * v1;
        float sc = v0 * w.x + v1 * w.y;
        #pragma unroll
        for (int off = 1; off < 64; off <<= 1) sc += __shfl_xor(sc, off);
        float mn = fmaxf(m, sc);
        float corr = __expf(m - mn);
        float pv = __expf(sc - mn);
        l = l * corr + pv;
        acc0 = acc0 * corr + pv * x0;
        acc1 = acc1 * corr + pv * x1;
        m = mn;
    }

    float inv = 1.f / (l + 1e-16f);
    int c0 = lane * 2, c1 = lane * 2 + 1;
    float h0 = acc0 * inv + bias2[c0];
    float h1v = acc1 * inv + bias2[c1];
    float a = h0 * Wa[c0] + h1v * Wa[c1];
    float r = h0 * Wrc[c0] + h1v * Wrc[c1];
    #pragma unroll
    for (int off = 1; off < 64; off <<= 1) {
        a += __shfl_xor(a, off);
        r += __shfl_xor(r, off);
    }
    if (lane == 0) {
        out[node]     = 1.f / (1.f + __expf(-(a + ba[0])));
        out[n + node] = 1.f / (1.f + __expf(-(r + brc[0])));
    }
}

// ---------------------------------------------------------------------------
extern "C" void kernel_launch(void* const* d_in, const int* in_sizes, int n_in,
                              void* d_out, int out_size, void* d_ws, size_t ws_size,
                              hipStream_t stream) {
    const float* x    = (const float*)d_in[0];
    const int* ei     = (const int*)d_in[1];
    const float* W1l  = (const float*)d_in[2];
    const float* b1l  = (const float*)d_in[3];
    const float* W1r  = (const float*)d_in[4];
    const float* b1r  = (const float*)d_in[5];
    const float* att1 = (const float*)d_in[6];
    const float* bias1= (const float*)d_in[7];
    const float* W2l  = (const float*)d_in[8];
    const float* b2l  = (const float*)d_in[9];
    const float* W2r  = (const float*)d_in[10];
    const float* b2r  = (const float*)d_in[11];
    const float* att2 = (const float*)d_in[12];
    const float* bias2= (const float*)d_in[13];
    const float* Wa   = (const float*)d_in[14];
    const float* ba   = (const float*)d_in[15];
    const float* Wrc  = (const float*)d_in[16];
    const float* brc  = (const float*)d_in[17];
    float* out = (float*)d_out;

    const int N = N_NODES, E = N_EDGES;
    const int* src = ei;
    const int* dst = ei + E;

    char* ws = (char*)d_ws;
    // xlr1: [MPAD][1024] bf16 = 41,156,608 B @ 0
    u16*   xlr1 = (u16*)ws;
    // h1b: [MPAD][512] bf16 @ 41,156,608 (20,578,304 B)
    u16*   h1b  = (u16*)(ws + 41156608);
    // xb: [MPAD][256] bf16 @ 61,734,912 (10,289,152 B); xlr2 reuses after gemm1
    u16*   xb   = (u16*)(ws + 61734912);
    u16*   xlr2 = (u16*)(ws + 61734912);
    // BT1 [1024][256] bf16 @ 72,024,064 (524,288); BT2 [256][512] @ 72,548,352 (262,144)
    u16*   BT1  = (u16*)(ws + 72024064);
    u16*   BT2  = (u16*)(ws + 72548352);
    float* bc1  = (float*)(ws + 72810496);            // 4096
    float* bc2  = (float*)(ws + 72814592);            // 1024
    int* deg       = (int*)(ws + 72815616);           // 80,000
    int* row_start = (int*)(ws + 72896000);           // 80,004
    int* cursor    = (int*)(ws + 72976128);           // 80,000
    int* ssrc      = (int*)(ws + 73056128);           // 1,280,000
    int* seid      = (int*)(ws + 74336128);           // 1,280,000
    // end ~75.6 MB (89.8 MB proven available)

    // --- CSR build (deterministic) ---
    hipMemsetAsync(deg, 0, N * sizeof(int), stream);
    hist_kernel<<<(E + 255) / 256, 256, 0, stream>>>(dst, deg, E);
    scan_kernel<<<1, 256, 0, stream>>>(deg, row_start, cursor, N);
    scatter_kernel<<<(E + 255) / 256, 256, 0, stream>>>(dst, cursor, seid, E);
    sort_kernel<<<(N + 255) / 256, 256, 0, stream>>>(row_start, seid, N);
    fill_kernel<<<(E + 255) / 256, 256, 0, stream>>>(seid, src, ssrc, E);

    // --- casts / weight prep ---
    cast_x_kernel<<<(MPAD * IN_DIM / 4 + 255) / 256, 256, 0, stream>>>(x, xb);
    dim3 tb(32, 8);
    transpose_cast_kernel<<<dim3(16, 8), tb, 0, stream>>>(W1l, BT1, 256, 512);
    transpose_cast_kernel<<<dim3(16, 8), tb, 0, stream>>>(W1r, BT1 + 512 * 256, 256, 512);
    transpose_cast_kernel<<<dim3(4, 16), tb, 0, stream>>>(W2l, BT2, 512, 128);
    transpose_cast_kernel<<<dim3(4, 16), tb, 0, stream>>>(W2r, BT2 + 128 * 512, 512, 128);
    prep_bias_kernel<<<1, 1024, 0, stream>>>(b1l, b1r, b2l, b2r, bc1, bc2);

    // --- layer 1 ---
    gemm_bf16_kernel<<<dim3(8, 157), 256, 0, stream>>>(xb, BT1, bc1, xlr1, 256, N, 1024);
    fused1_kernel<<<(N + 3) / 4, 256, 0, stream>>>(xlr1, row_start, ssrc, att1, bias1, h1b, N);

    // --- layer 2 + heads ---
    gemm_bf16_kernel<<<dim3(2, 157), 256, 0, stream>>>(h1b, BT2, bc2, xlr2, 512, N, 256);
    fused2_kernel<<<(N + 3) / 4, 256, 0, stream>>>(xlr2, row_start, ssrc, att2, bias2,
                                                   Wa, ba, Wrc, brc, out, N);
}

// Round 8
// 301.701 us; speedup vs baseline: 2.8878x; 1.1050x over previous
//
#include <hip/hip_runtime.h>
#include <hip/hip_bf16.h>

#define N_NODES 20000
#define N_EDGES 320000
#define IN_DIM 256
#define HID 128
#define HEADS 4
#define MPAD 20096   // 157 * 128

typedef unsigned short u16;
typedef __attribute__((ext_vector_type(8))) short bf16x8;
typedef __attribute__((ext_vector_type(4))) float f32x4;
typedef __attribute__((address_space(1))) void g_void;
typedef __attribute__((address_space(3))) void l_void;

__device__ __forceinline__ float asf(unsigned int u) {
    union { unsigned int i; float f; } c; c.i = u; return c.f;
}
__device__ __forceinline__ float bflo(unsigned int u) { return asf(u << 16); }
__device__ __forceinline__ float bfhi(unsigned int u) { return asf(u & 0xffff0000u); }
__device__ __forceinline__ u16 f2bf(float f) {
    union { float f; unsigned int i; } c; c.f = f;
    return (u16)((c.i + 0x7FFF + ((c.i >> 16) & 1)) >> 16);   // RNE
}

// ---------------------------------------------------------------------------
// CSR build: histogram -> scan -> scatter(eid) -> per-segment sort+fill
// Deterministic: segments sorted by original edge index every call.
// ---------------------------------------------------------------------------
__global__ void hist_kernel(const int* __restrict__ dst, int* __restrict__ deg, int E) {
    int i = blockIdx.x * blockDim.x + threadIdx.x;
    if (i < E) atomicAdd(&deg[dst[i]], 1);
}

__global__ __launch_bounds__(1024) void scan_kernel(
    const int* __restrict__ deg, int* __restrict__ row_start,
    int* __restrict__ cursor, int n) {
    __shared__ int partial[1024];
    int t = threadIdx.x;
    int chunk = (n + 1023) / 1024;
    int begin = t * chunk;
    int end = min(begin + chunk, n);
    int s = 0;
    for (int i = begin; i < end; ++i) s += deg[i];
    partial[t] = s;
    __syncthreads();
    for (int off = 1; off < 1024; off <<= 1) {
        int v = (t >= off) ? partial[t - off] : 0;
        __syncthreads();
        partial[t] += v;
        __syncthreads();
    }
    int run = (t == 0) ? 0 : partial[t - 1];
    for (int i = begin; i < end; ++i) {
        row_start[i] = run;
        cursor[i] = run;
        run += deg[i];
    }
    if (t == 1023) row_start[n] = run;
}

__global__ void scatter_kernel(const int* __restrict__ dst, int* __restrict__ cursor,
                               int* __restrict__ seid, int E) {
    int i = blockIdx.x * blockDim.x + threadIdx.x;
    if (i < E) {
        int pos = atomicAdd(&cursor[dst[i]], 1);
        seid[pos] = i;
    }
}

__global__ void sortfill_kernel(const int* __restrict__ row_start, int* __restrict__ seid,
                                const int* __restrict__ src, int* __restrict__ ssrc, int n) {
    int node = blockIdx.x * blockDim.x + threadIdx.x;
    if (node >= n) return;
    int beg = row_start[node], end = row_start[node + 1];
    for (int i = beg + 1; i < end; ++i) {
        int v = seid[i];
        int j = i - 1;
        while (j >= beg && seid[j] > v) { seid[j + 1] = seid[j]; --j; }
        seid[j + 1] = v;
    }
    for (int i = beg; i < end; ++i) ssrc[i] = src[seid[i]];
}

// ---------------------------------------------------------------------------
// cast x (fp32 [20000][256]) -> bf16 [MPAD][256], pad rows zeroed
// ---------------------------------------------------------------------------
__global__ void cast_x_kernel(const float* __restrict__ x, u16* __restrict__ xb) {
    int i = blockIdx.x * blockDim.x + threadIdx.x;     // quad id
    const int nq = MPAD * IN_DIM / 4;
    if (i >= nq) return;
    int elem = i * 4;
    uint2 u;
    if (elem < N_NODES * IN_DIM) {
        float4 v = ((const float4*)x)[i];
        u.x = (unsigned)f2bf(v.x) | ((unsigned)f2bf(v.y) << 16);
        u.y = (unsigned)f2bf(v.z) | ((unsigned)f2bf(v.w) << 16);
    } else {
        u.x = 0u; u.y = 0u;
    }
    *(uint2*)(xb + elem) = u;
}

// ---------------------------------------------------------------------------
// transpose+cast all four weights: W fp32 [K][N] -> out bf16 [N][K]
// blockIdx.z selects the matrix; grid (16,16,4), early-out on overshoot.
// ---------------------------------------------------------------------------
__global__ __launch_bounds__(256) void transpose_all_kernel(
    const float* __restrict__ W1l, const float* __restrict__ W1r,
    const float* __restrict__ W2l, const float* __restrict__ W2r,
    u16* __restrict__ BT1, u16* __restrict__ BT2) {
    const float* W; u16* out; int K, N;
    switch (blockIdx.z) {
        case 0:  W = W1l; out = BT1;             K = 256; N = 512; break;
        case 1:  W = W1r; out = BT1 + 512 * 256; K = 256; N = 512; break;
        case 2:  W = W2l; out = BT2;             K = 512; N = 128; break;
        default: W = W2r; out = BT2 + 128 * 512; K = 512; N = 128; break;
    }
    int bx = blockIdx.x * 32;   // n base
    int by = blockIdx.y * 32;   // k base
    if (bx >= N || by >= K) return;
    __shared__ float t[32][33];
    int tx = threadIdx.x, ty = threadIdx.y;
    #pragma unroll
    for (int j = 0; j < 32; j += 8)
        t[ty + j][tx] = W[(size_t)(by + ty + j) * N + bx + tx];
    __syncthreads();
    #pragma unroll
    for (int j = 0; j < 32; j += 8)
        out[(size_t)(bx + ty + j) * K + by + tx] = f2bf(t[tx][ty + j]);
}

// ---------------------------------------------------------------------------
// concat biases (fp32)
// ---------------------------------------------------------------------------
__global__ void prep_bias_kernel(const float* b1l, const float* b1r,
                                 const float* b2l, const float* b2r,
                                 float* bc1, float* bc2) {
    int t = threadIdx.x;   // one block of 1024
    if (t < 512) bc1[t] = b1l[t];
    else bc1[t] = b1r[t - 512];
    if (t < 128) bc2[t] = b2l[t];
    else if (t < 256) bc2[t] = b2r[t - 128];
}

// ---------------------------------------------------------------------------
// bf16 MFMA GEMM: C[Mrows][N] = A[MPAD][K] @ BT[N][K]^T + bias, bf16 out
// tile 128x128, BK=32, 256 threads (4 waves 2x2), 4x4 16x16 frags per wave
// ---------------------------------------------------------------------------
__global__ __launch_bounds__(256) void gemm_bf16_kernel(
    const u16* __restrict__ A, const u16* __restrict__ BT,
    const float* __restrict__ bias, u16* __restrict__ C,
    int K, int Mrows, int N) {
    __shared__ u16 As[4096];
    __shared__ u16 Bs[4096];
    const int tid = threadIdx.x;
    const int lane = tid & 63;
    const int wid = tid >> 6;
    const int wr = wid >> 1, wc = wid & 1;
    const int brow = blockIdx.y * 128, bcol = blockIdx.x * 128;

    const int srow = tid >> 2;
    const int skk = (((tid & 3) ^ ((tid >> 3) & 3))) * 8;
    const u16* ga0 = A + (size_t)(brow + srow) * K + skk;
    const u16* ga1 = A + (size_t)(brow + 64 + srow) * K + skk;
    const u16* gb0 = BT + (size_t)(bcol + srow) * K + skk;
    const u16* gb1 = BT + (size_t)(bcol + 64 + srow) * K + skk;
    u16* lA0 = As + tid * 8;
    u16* lA1 = As + 2048 + tid * 8;
    u16* lB0 = Bs + tid * 8;
    u16* lB1 = Bs + 2048 + tid * 8;

    const int fr = lane & 15;
    const int fg = lane >> 4;
    const int fslot = (fg ^ ((fr >> 1) & 3)) * 8;
    const u16* ra = As + (wr * 64 + fr) * 32 + fslot;
    const u16* rb = Bs + (wc * 64 + fr) * 32 + fslot;

    f32x4 acc[4][4];
    #pragma unroll
    for (int m = 0; m < 4; ++m)
        #pragma unroll
        for (int n = 0; n < 4; ++n)
            acc[m][n] = (f32x4){0.f, 0.f, 0.f, 0.f};

    for (int k0 = 0; k0 < K; k0 += 32) {
        __builtin_amdgcn_global_load_lds((const g_void*)(ga0 + k0), (l_void*)lA0, 16, 0, 0);
        __builtin_amdgcn_global_load_lds((const g_void*)(ga1 + k0), (l_void*)lA1, 16, 0, 0);
        __builtin_amdgcn_global_load_lds((const g_void*)(gb0 + k0), (l_void*)lB0, 16, 0, 0);
        __builtin_amdgcn_global_load_lds((const g_void*)(gb1 + k0), (l_void*)lB1, 16, 0, 0);
        __syncthreads();
        bf16x8 av[4], bv[4];
        #pragma unroll
        for (int m = 0; m < 4; ++m) av[m] = *(const bf16x8*)(ra + m * 512);
        #pragma unroll
        for (int n = 0; n < 4; ++n) bv[n] = *(const bf16x8*)(rb + n * 512);
        #pragma unroll
        for (int m = 0; m < 4; ++m)
            #pragma unroll
            for (int n = 0; n < 4; ++n)
                acc[m][n] = __builtin_amdgcn_mfma_f32_16x16x32_bf16(av[m], bv[n], acc[m][n], 0, 0, 0);
        __syncthreads();
    }

    const int col0 = bcol + wc * 64 + fr;
    const int row0 = brow + wr * 64 + fg * 4;
    #pragma unroll
    for (int n = 0; n < 4; ++n) {
        const int col = col0 + n * 16;
        const float bv2 = bias[col];
        #pragma unroll
        for (int m = 0; m < 4; ++m) {
            const int r0 = row0 + m * 16;
            #pragma unroll
            for (int j = 0; j < 4; ++j) {
                int r = r0 + j;
                if (r < Mrows) C[(size_t)r * N + col] = f2bf(acc[m][n][j] + bv2);
            }
        }
    }
}

// ---------------------------------------------------------------------------
// fused layer-1 edge phase: one wave per node, no-shift softmax (scores are
// O(1); fp32 exp overflows only past 88 — huge margin). 2-edge unroll with
// dual prefetch; all branches wave-uniform. Epilogue: /denom, +bias1, ELU.
// ---------------------------------------------------------------------------
#define UNPACK8(c, f) \
    f[0] = bflo(c.x); f[1] = bfhi(c.x); f[2] = bflo(c.y); f[3] = bfhi(c.y); \
    f[4] = bflo(c.z); f[5] = bfhi(c.z); f[6] = bflo(c.w); f[7] = bfhi(c.w);

__global__ __launch_bounds__(256) void fused1_kernel(
    const u16* __restrict__ xlr, const int* __restrict__ row_start,
    const int* __restrict__ ssrc, const float* __restrict__ att1,
    const float* __restrict__ bias1, u16* __restrict__ h1, int n) {
    int node = blockIdx.x * 4 + (threadIdx.x >> 6);
    int lane = threadIdx.x & 63;
    if (node >= n) return;

    uint4 xr4 = *(const uint4*)(xlr + (size_t)node * 1024 + 512 + lane * 8);
    float xrf[8];
    UNPACK8(xr4, xrf);
    float4 w0 = ((const float4*)att1)[lane * 2];
    float4 w1 = ((const float4*)att1)[lane * 2 + 1];
    float wa[8] = {w0.x, w0.y, w0.z, w0.w, w1.x, w1.y, w1.z, w1.w};

    int beg = row_start[node], end = row_start[node + 1];
    float l = 0.f;
    float acc[8] = {0.f, 0.f, 0.f, 0.f, 0.f, 0.f, 0.f, 0.f};

    uint4 v0 = {0, 0, 0, 0}, v1 = {0, 0, 0, 0};
    if (beg < end)     v0 = *(const uint4*)(xlr + (size_t)ssrc[beg] * 1024 + lane * 8);
    if (beg + 1 < end) v1 = *(const uint4*)(xlr + (size_t)ssrc[beg + 1] * 1024 + lane * 8);

    for (int p = beg; p < end; p += 2) {
        uint4 c0 = v0, c1 = v1;
        if (p + 2 < end) v0 = *(const uint4*)(xlr + (size_t)ssrc[p + 2] * 1024 + lane * 8);
        if (p + 3 < end) v1 = *(const uint4*)(xlr + (size_t)ssrc[p + 3] * 1024 + lane * 8);

        float xf[8];
        UNPACK8(c0, xf);
        float sc = 0.f;
        #pragma unroll
        for (int j = 0; j < 8; ++j) {
            float v = xf[j] + xrf[j];
            sc = fmaf(fmaxf(v, 0.2f * v), wa[j], sc);
        }
        sc += __shfl_xor(sc, 1);
        sc += __shfl_xor(sc, 2);
        sc += __shfl_xor(sc, 4);
        sc += __shfl_xor(sc, 8);
        float pv = __expf(sc);
        l += pv;
        #pragma unroll
        for (int j = 0; j < 8; ++j) acc[j] = fmaf(pv, xf[j], acc[j]);

        if (p + 1 < end) {
            float yf[8];
            UNPACK8(c1, yf);
            float sc1 = 0.f;
            #pragma unroll
            for (int j = 0; j < 8; ++j) {
                float v = yf[j] + xrf[j];
                sc1 = fmaf(fmaxf(v, 0.2f * v), wa[j], sc1);
            }
            sc1 += __shfl_xor(sc1, 1);
            sc1 += __shfl_xor(sc1, 2);
            sc1 += __shfl_xor(sc1, 4);
            sc1 += __shfl_xor(sc1, 8);
            float pv1 = __expf(sc1);
            l += pv1;
            #pragma unroll
            for (int j = 0; j < 8; ++j) acc[j] = fmaf(pv1, yf[j], acc[j]);
        }
    }

    float inv = 1.f / (l + 1e-16f);
    float4 b0 = ((const float4*)bias1)[lane * 2];
    float4 b1 = ((const float4*)bias1)[lane * 2 + 1];
    float bb[8] = {b0.x, b0.y, b0.z, b0.w, b1.x, b1.y, b1.z, b1.w};
    bf16x8 outv;
    #pragma unroll
    for (int j = 0; j < 8; ++j) {
        float v = fmaf(acc[j], inv, bb[j]);
        v = v > 0.f ? v : __expf(v) - 1.f;   // ELU
        outv[j] = (short)f2bf(v);
    }
    *(bf16x8*)(h1 + (size_t)node * 512 + lane * 8) = outv;
}

// ---------------------------------------------------------------------------
// fused layer-2 edge phase + heads: one wave per node, no-shift softmax,
// 2-edge unroll, then anomaly/root-cause dots + sigmoid.
// ---------------------------------------------------------------------------
__global__ __launch_bounds__(256) void fused2_kernel(
    const u16* __restrict__ xlr2, const int* __restrict__ row_start,
    const int* __restrict__ ssrc, const float* __restrict__ att2,
    const float* __restrict__ bias2, const float* __restrict__ Wa,
    const float* __restrict__ ba, const float* __restrict__ Wrc,
    const float* __restrict__ brc, float* __restrict__ out, int n) {
    int node = blockIdx.x * 4 + (threadIdx.x >> 6);
    int lane = threadIdx.x & 63;
    if (node >= n) return;

    unsigned int xr = *(const unsigned int*)(xlr2 + (size_t)node * 256 + 128 + lane * 2);
    float xr0 = bflo(xr), xr1 = bfhi(xr);
    float2 w = ((const float2*)att2)[lane];

    int beg = row_start[node], end = row_start[node + 1];
    float l = 0.f, acc0 = 0.f, acc1 = 0.f;

    unsigned int v0 = 0, v1 = 0;
    if (beg < end)     v0 = *(const unsigned int*)(xlr2 + (size_t)ssrc[beg] * 256 + lane * 2);
    if (beg + 1 < end) v1 = *(const unsigned int*)(xlr2 + (size_t)ssrc[beg + 1] * 256 + lane * 2);

    for (int p = beg; p < end; p += 2) {
        unsigned int c0 = v0, c1 = v1;
        if (p + 2 < end) v0 = *(const unsigned int*)(xlr2 + (size_t)ssrc[p + 2] * 256 + lane * 2);
        if (p + 3 < end) v1 = *(const unsigned int*)(xlr2 + (size_t)ssrc[p + 3] * 256 + lane * 2);

        float x0 = bflo(c0), x1 = bfhi(c0);
        float t0 = x0 + xr0, t1 = x1 + xr1;
        float sc = fmaxf(t0, 0.2f * t0) * w.x + fmaxf(t1, 0.2f * t1) * w.y;
        #pragma unroll
        for (int off = 1; off < 64; off <<= 1) sc += __shfl_xor(sc, off);
        float pv = __expf(sc);
        l += pv;
        acc0 = fmaf(pv, x0, acc0);
        acc1 = fmaf(pv, x1, acc1);

        if (p + 1 < end) {
            float y0 = bflo(c1), y1 = bfhi(c1);
            float u0 = y0 + xr0, u1 = y1 + xr1;
            float sc1 = fmaxf(u0, 0.2f * u0) * w.x + fmaxf(u1, 0.2f * u1) * w.y;
            #pragma unroll
            for (int off = 1; off < 64; off <<= 1) sc1 += __shfl_xor(sc1, off);
            float pv1 = __expf(sc1);
            l += pv1;
            acc0 = fmaf(pv1, y0, acc0);
            acc1 = fmaf(pv1, y1, acc1);
        }
    }

    float inv = 1.f / (l + 1e-16f);
    int c0i = lane * 2, c1i = lane * 2 + 1;
    float h0 = fmaf(acc0, inv, bias2[c0i]);
    float h1v = fmaf(acc1, inv, bias2[c1i]);
    float a = h0 * Wa[c0i] + h1v * Wa[c1i];
    float r = h0 * Wrc[c0i] + h1v * Wrc[c1i];
    #pragma unroll
    for (int off = 1; off < 64; off <<= 1) {
        a += __shfl_xor(a, off);
        r += __shfl_xor(r, off);
    }
    if (lane == 0) {
        out[node]     = 1.f / (1.f + __expf(-(a + ba[0])));
        out[n + node] = 1.f / (1.f + __expf(-(r + brc[0])));
    }
}

// ---------------------------------------------------------------------------
extern "C" void kernel_launch(void* const* d_in, const int* in_sizes, int n_in,
                              void* d_out, int out_size, void* d_ws, size_t ws_size,
                              hipStream_t stream) {
    const float* x    = (const float*)d_in[0];
    const int* ei     = (const int*)d_in[1];
    const float* W1l  = (const float*)d_in[2];
    const float* b1l  = (const float*)d_in[3];
    const float* W1r  = (const float*)d_in[4];
    const float* b1r  = (const float*)d_in[5];
    const float* att1 = (const float*)d_in[6];
    const float* bias1= (const float*)d_in[7];
    const float* W2l  = (const float*)d_in[8];
    const float* b2l  = (const float*)d_in[9];
    const float* W2r  = (const float*)d_in[10];
    const float* b2r  = (const float*)d_in[11];
    const float* att2 = (const float*)d_in[12];
    const float* bias2= (const float*)d_in[13];
    const float* Wa   = (const float*)d_in[14];
    const float* ba   = (const float*)d_in[15];
    const float* Wrc  = (const float*)d_in[16];
    const float* brc  = (const float*)d_in[17];
    float* out = (float*)d_out;

    const int N = N_NODES, E = N_EDGES;
    const int* src = ei;
    const int* dst = ei + E;

    char* ws = (char*)d_ws;
    u16*   xlr1 = (u16*)ws;                           // [MPAD][1024] bf16 = 41,156,608
    u16*   h1b  = (u16*)(ws + 41156608);              // [MPAD][512] bf16 = 20,578,304
    u16*   xb   = (u16*)(ws + 61734912);              // [MPAD][256] bf16 = 10,289,152
    u16*   xlr2 = (u16*)(ws + 61734912);              // reuses xb after gemm1
    u16*   BT1  = (u16*)(ws + 72024064);              // [1024][256] bf16 = 524,288
    u16*   BT2  = (u16*)(ws + 72548352);              // [256][512] bf16 = 262,144
    float* bc1  = (float*)(ws + 72810496);            // 4096
    float* bc2  = (float*)(ws + 72814592);            // 1024
    int* deg       = (int*)(ws + 72815616);           // 80,000
    int* row_start = (int*)(ws + 72896000);           // 80,004
    int* cursor    = (int*)(ws + 72976128);           // 80,000
    int* ssrc      = (int*)(ws + 73056128);           // 1,280,000
    int* seid      = (int*)(ws + 74336128);           // 1,280,000
    // end ~75.6 MB (89.8 MB proven available)

    // --- CSR build (deterministic) ---
    hipMemsetAsync(deg, 0, N * sizeof(int), stream);
    hist_kernel<<<(E + 255) / 256, 256, 0, stream>>>(dst, deg, E);
    scan_kernel<<<1, 1024, 0, stream>>>(deg, row_start, cursor, N);
    scatter_kernel<<<(E + 255) / 256, 256, 0, stream>>>(dst, cursor, seid, E);
    sortfill_kernel<<<(N + 255) / 256, 256, 0, stream>>>(row_start, seid, src, ssrc, N);

    // --- casts / weight prep ---
    cast_x_kernel<<<(MPAD * IN_DIM / 4 + 255) / 256, 256, 0, stream>>>(x, xb);
    transpose_all_kernel<<<dim3(16, 16, 4), dim3(32, 8), 0, stream>>>(
        W1l, W1r, W2l, W2r, BT1, BT2);
    prep_bias_kernel<<<1, 1024, 0, stream>>>(b1l, b1r, b2l, b2r, bc1, bc2);

    // --- layer 1 ---
    gemm_bf16_kernel<<<dim3(8, 157), 256, 0, stream>>>(xb, BT1, bc1, xlr1, 256, N, 1024);
    fused1_kernel<<<(N + 3) / 4, 256, 0, stream>>>(xlr1, row_start, ssrc, att1, bias1, h1b, N);

    // --- layer 2 + heads ---
    gemm_bf16_kernel<<<dim3(2, 157), 256, 0, stream>>>(h1b, BT2, bc2, xlr2, 512, N, 256);
    fused2_kernel<<<(N + 3) / 4, 256, 0, stream>>>(xlr2, row_start, ssrc, att2, bias2,
                                                   Wa, ba, Wrc, brc, out, N);
}

// Round 9
// 250.983 us; speedup vs baseline: 3.4714x; 1.2021x over previous
//
#include <hip/hip_runtime.h>
#include <hip/hip_bf16.h>

#define N_NODES 20000
#define N_EDGES 320000
#define IN_DIM 256
#define HID 128
#define HEADS 4
#define MPAD 20096   // 157 * 128

typedef unsigned short u16;
typedef __attribute__((ext_vector_type(8))) short bf16x8;
typedef __attribute__((ext_vector_type(4))) float f32x4;
typedef __attribute__((address_space(1))) void g_void;
typedef __attribute__((address_space(3))) void l_void;

__device__ __forceinline__ float asf(unsigned int u) {
    union { unsigned int i; float f; } c; c.i = u; return c.f;
}
__device__ __forceinline__ float bflo(unsigned int u) { return asf(u << 16); }
__device__ __forceinline__ float bfhi(unsigned int u) { return asf(u & 0xffff0000u); }
__device__ __forceinline__ u16 f2bf(float f) {
    union { float f; unsigned int i; } c; c.f = f;
    return (u16)((c.i + 0x7FFF + ((c.i >> 16) & 1)) >> 16);   // RNE
}

// ---------------------------------------------------------------------------
// CSR build: histogram -> scan -> scatter(eid,dst) -> parallel rank+fill
// Deterministic: final ssrc order within each segment is ascending edge id,
// computed by rank-counting (IDs distinct -> no ties), independent of the
// atomic scatter's arrival order.
// ---------------------------------------------------------------------------
__global__ void hist_kernel(const int* __restrict__ dst, int* __restrict__ deg, int E) {
    int i = blockIdx.x * blockDim.x + threadIdx.x;
    if (i < E) atomicAdd(&deg[dst[i]], 1);
}

__global__ __launch_bounds__(1024) void scan_kernel(
    const int* __restrict__ deg, int* __restrict__ row_start,
    int* __restrict__ cursor, int n) {
    __shared__ int partial[1024];
    int t = threadIdx.x;
    int chunk = (n + 1023) / 1024;
    int begin = t * chunk;
    int end = min(begin + chunk, n);
    int s = 0;
    for (int i = begin; i < end; ++i) s += deg[i];
    partial[t] = s;
    __syncthreads();
    for (int off = 1; off < 1024; off <<= 1) {
        int v = (t >= off) ? partial[t - off] : 0;
        __syncthreads();
        partial[t] += v;
        __syncthreads();
    }
    int run = (t == 0) ? 0 : partial[t - 1];
    for (int i = begin; i < end; ++i) {
        row_start[i] = run;
        cursor[i] = run;
        run += deg[i];
    }
    if (t == 1023) row_start[n] = run;
}

__global__ void scatter_kernel(const int* __restrict__ dst, int* __restrict__ cursor,
                               int* __restrict__ seid, int* __restrict__ sdst, int E) {
    int i = blockIdx.x * blockDim.x + threadIdx.x;
    if (i < E) {
        int d = dst[i];
        int pos = atomicAdd(&cursor[d], 1);
        seid[pos] = i;
        sdst[pos] = d;
    }
}

__global__ void rank_kernel(const int* __restrict__ row_start, const int* __restrict__ seid,
                            const int* __restrict__ sdst, const int* __restrict__ src,
                            int* __restrict__ ssrc, int E) {
    int i = blockIdx.x * blockDim.x + threadIdx.x;
    if (i >= E) return;
    int d = sdst[i];
    int beg = row_start[d], end = row_start[d + 1];
    int my = seid[i];
    int rank = 0;
    for (int j = beg; j < end; ++j) rank += (seid[j] < my) ? 1 : 0;
    ssrc[beg + rank] = src[my];
}

// ---------------------------------------------------------------------------
// cast x (fp32 [20000][256]) -> bf16 [MPAD][256], pad rows zeroed
// ---------------------------------------------------------------------------
__global__ void cast_x_kernel(const float* __restrict__ x, u16* __restrict__ xb) {
    int i = blockIdx.x * blockDim.x + threadIdx.x;     // quad id
    const int nq = MPAD * IN_DIM / 4;
    if (i >= nq) return;
    int elem = i * 4;
    uint2 u;
    if (elem < N_NODES * IN_DIM) {
        float4 v = ((const float4*)x)[i];
        u.x = (unsigned)f2bf(v.x) | ((unsigned)f2bf(v.y) << 16);
        u.y = (unsigned)f2bf(v.z) | ((unsigned)f2bf(v.w) << 16);
    } else {
        u.x = 0u; u.y = 0u;
    }
    *(uint2*)(xb + elem) = u;
}

// ---------------------------------------------------------------------------
// transpose+cast all four weights: W fp32 [K][N] -> out bf16 [N][K]
// ---------------------------------------------------------------------------
__global__ __launch_bounds__(256) void transpose_all_kernel(
    const float* __restrict__ W1l, const float* __restrict__ W1r,
    const float* __restrict__ W2l, const float* __restrict__ W2r,
    u16* __restrict__ BT1, u16* __restrict__ BT2) {
    const float* W; u16* out; int K, N;
    switch (blockIdx.z) {
        case 0:  W = W1l; out = BT1;             K = 256; N = 512; break;
        case 1:  W = W1r; out = BT1 + 512 * 256; K = 256; N = 512; break;
        case 2:  W = W2l; out = BT2;             K = 512; N = 128; break;
        default: W = W2r; out = BT2 + 128 * 512; K = 512; N = 128; break;
    }
    int bx = blockIdx.x * 32;   // n base
    int by = blockIdx.y * 32;   // k base
    if (bx >= N || by >= K) return;
    __shared__ float t[32][33];
    int tx = threadIdx.x, ty = threadIdx.y;
    #pragma unroll
    for (int j = 0; j < 32; j += 8)
        t[ty + j][tx] = W[(size_t)(by + ty + j) * N + bx + tx];
    __syncthreads();
    #pragma unroll
    for (int j = 0; j < 32; j += 8)
        out[(size_t)(bx + ty + j) * K + by + tx] = f2bf(t[tx][ty + j]);
}

// ---------------------------------------------------------------------------
// concat biases (fp32)
// ---------------------------------------------------------------------------
__global__ void prep_bias_kernel(const float* b1l, const float* b1r,
                                 const float* b2l, const float* b2r,
                                 float* bc1, float* bc2) {
    int t = threadIdx.x;   // one block of 1024
    if (t < 512) bc1[t] = b1l[t];
    else bc1[t] = b1r[t - 512];
    if (t < 128) bc2[t] = b2l[t];
    else if (t < 256) bc2[t] = b2r[t - 128];
}

// ---------------------------------------------------------------------------
// bf16 MFMA GEMM: C[Mrows][N] = A[MPAD][K] @ BT[N][K]^T + bias, bf16 out
// tile 128x128, BK=32, 256 threads (4 waves 2x2), 4x4 16x16 frags per wave
// ---------------------------------------------------------------------------
__global__ __launch_bounds__(256) void gemm_bf16_kernel(
    const u16* __restrict__ A, const u16* __restrict__ BT,
    const float* __restrict__ bias, u16* __restrict__ C,
    int K, int Mrows, int N) {
    __shared__ u16 As[4096];
    __shared__ u16 Bs[4096];
    const int tid = threadIdx.x;
    const int lane = tid & 63;
    const int wid = tid >> 6;
    const int wr = wid >> 1, wc = wid & 1;
    const int brow = blockIdx.y * 128, bcol = blockIdx.x * 128;

    const int srow = tid >> 2;
    const int skk = (((tid & 3) ^ ((tid >> 3) & 3))) * 8;
    const u16* ga0 = A + (size_t)(brow + srow) * K + skk;
    const u16* ga1 = A + (size_t)(brow + 64 + srow) * K + skk;
    const u16* gb0 = BT + (size_t)(bcol + srow) * K + skk;
    const u16* gb1 = BT + (size_t)(bcol + 64 + srow) * K + skk;
    u16* lA0 = As + tid * 8;
    u16* lA1 = As + 2048 + tid * 8;
    u16* lB0 = Bs + tid * 8;
    u16* lB1 = Bs + 2048 + tid * 8;

    const int fr = lane & 15;
    const int fg = lane >> 4;
    const int fslot = (fg ^ ((fr >> 1) & 3)) * 8;
    const u16* ra = As + (wr * 64 + fr) * 32 + fslot;
    const u16* rb = Bs + (wc * 64 + fr) * 32 + fslot;

    f32x4 acc[4][4];
    #pragma unroll
    for (int m = 0; m < 4; ++m)
        #pragma unroll
        for (int n = 0; n < 4; ++n)
            acc[m][n] = (f32x4){0.f, 0.f, 0.f, 0.f};

    for (int k0 = 0; k0 < K; k0 += 32) {
        __builtin_amdgcn_global_load_lds((const g_void*)(ga0 + k0), (l_void*)lA0, 16, 0, 0);
        __builtin_amdgcn_global_load_lds((const g_void*)(ga1 + k0), (l_void*)lA1, 16, 0, 0);
        __builtin_amdgcn_global_load_lds((const g_void*)(gb0 + k0), (l_void*)lB0, 16, 0, 0);
        __builtin_amdgcn_global_load_lds((const g_void*)(gb1 + k0), (l_void*)lB1, 16, 0, 0);
        __syncthreads();
        bf16x8 av[4], bv[4];
        #pragma unroll
        for (int m = 0; m < 4; ++m) av[m] = *(const bf16x8*)(ra + m * 512);
        #pragma unroll
        for (int n = 0; n < 4; ++n) bv[n] = *(const bf16x8*)(rb + n * 512);
        #pragma unroll
        for (int m = 0; m < 4; ++m)
            #pragma unroll
            for (int n = 0; n < 4; ++n)
                acc[m][n] = __builtin_amdgcn_mfma_f32_16x16x32_bf16(av[m], bv[n], acc[m][n], 0, 0, 0);
        __syncthreads();
    }

    const int col0 = bcol + wc * 64 + fr;
    const int row0 = brow + wr * 64 + fg * 4;
    #pragma unroll
    for (int n = 0; n < 4; ++n) {
        const int col = col0 + n * 16;
        const float bv2 = bias[col];
        #pragma unroll
        for (int m = 0; m < 4; ++m) {
            const int r0 = row0 + m * 16;
            #pragma unroll
            for (int j = 0; j < 4; ++j) {
                int r = r0 + j;
                if (r < Mrows) C[(size_t)r * N + col] = f2bf(acc[m][n][j] + bv2);
            }
        }
    }
}

// ---------------------------------------------------------------------------
// fused layer-1 edge phase: one wave per node, no-shift softmax (scores are
// O(1); fp32 exp overflows only past 88 — huge margin). 2-edge unroll with
// dual prefetch; all branches wave-uniform. Epilogue: /denom, +bias1, ELU.
// ---------------------------------------------------------------------------
#define UNPACK8(c, f) \
    f[0] = bflo(c.x); f[1] = bfhi(c.x); f[2] = bflo(c.y); f[3] = bfhi(c.y); \
    f[4] = bflo(c.z); f[5] = bfhi(c.z); f[6] = bflo(c.w); f[7] = bfhi(c.w);

__global__ __launch_bounds__(256) void fused1_kernel(
    const u16* __restrict__ xlr, const int* __restrict__ row_start,
    const int* __restrict__ ssrc, const float* __restrict__ att1,
    const float* __restrict__ bias1, u16* __restrict__ h1, int n) {
    int node = blockIdx.x * 4 + (threadIdx.x >> 6);
    int lane = threadIdx.x & 63;
    if (node >= n) return;

    uint4 xr4 = *(const uint4*)(xlr + (size_t)node * 1024 + 512 + lane * 8);
    float xrf[8];
    UNPACK8(xr4, xrf);
    float4 w0 = ((const float4*)att1)[lane * 2];
    float4 w1 = ((const float4*)att1)[lane * 2 + 1];
    float wa[8] = {w0.x, w0.y, w0.z, w0.w, w1.x, w1.y, w1.z, w1.w};

    int beg = row_start[node], end = row_start[node + 1];
    float l = 0.f;
    float acc[8] = {0.f, 0.f, 0.f, 0.f, 0.f, 0.f, 0.f, 0.f};

    uint4 v0 = {0, 0, 0, 0}, v1 = {0, 0, 0, 0};
    if (beg < end)     v0 = *(const uint4*)(xlr + (size_t)ssrc[beg] * 1024 + lane * 8);
    if (beg + 1 < end) v1 = *(const uint4*)(xlr + (size_t)ssrc[beg + 1] * 1024 + lane * 8);

    for (int p = beg; p < end; p += 2) {
        uint4 c0 = v0, c1 = v1;
        if (p + 2 < end) v0 = *(const uint4*)(xlr + (size_t)ssrc[p + 2] * 1024 + lane * 8);
        if (p + 3 < end) v1 = *(const uint4*)(xlr + (size_t)ssrc[p + 3] * 1024 + lane * 8);

        float xf[8];
        UNPACK8(c0, xf);
        float sc = 0.f;
        #pragma unroll
        for (int j = 0; j < 8; ++j) {
            float v = xf[j] + xrf[j];
            sc = fmaf(fmaxf(v, 0.2f * v), wa[j], sc);
        }
        sc += __shfl_xor(sc, 1);
        sc += __shfl_xor(sc, 2);
        sc += __shfl_xor(sc, 4);
        sc += __shfl_xor(sc, 8);
        float pv = __expf(sc);
        l += pv;
        #pragma unroll
        for (int j = 0; j < 8; ++j) acc[j] = fmaf(pv, xf[j], acc[j]);

        if (p + 1 < end) {
            float yf[8];
            UNPACK8(c1, yf);
            float sc1 = 0.f;
            #pragma unroll
            for (int j = 0; j < 8; ++j) {
                float v = yf[j] + xrf[j];
                sc1 = fmaf(fmaxf(v, 0.2f * v), wa[j], sc1);
            }
            sc1 += __shfl_xor(sc1, 1);
            sc1 += __shfl_xor(sc1, 2);
            sc1 += __shfl_xor(sc1, 4);
            sc1 += __shfl_xor(sc1, 8);
            float pv1 = __expf(sc1);
            l += pv1;
            #pragma unroll
            for (int j = 0; j < 8; ++j) acc[j] = fmaf(pv1, yf[j], acc[j]);
        }
    }

    float inv = 1.f / (l + 1e-16f);
    float4 b0 = ((const float4*)bias1)[lane * 2];
    float4 b1 = ((const float4*)bias1)[lane * 2 + 1];
    float bb[8] = {b0.x, b0.y, b0.z, b0.w, b1.x, b1.y, b1.z, b1.w};
    bf16x8 outv;
    #pragma unroll
    for (int j = 0; j < 8; ++j) {
        float v = fmaf(acc[j], inv, bb[j]);
        v = v > 0.f ? v : __expf(v) - 1.f;   // ELU
        outv[j] = (short)f2bf(v);
    }
    *(bf16x8*)(h1 + (size_t)node * 512 + lane * 8) = outv;
}

// ---------------------------------------------------------------------------
// fused layer-2 edge phase + heads: one wave per node, no-shift softmax,
// 2-edge unroll, then anomaly/root-cause dots + sigmoid.
// ---------------------------------------------------------------------------
__global__ __launch_bounds__(256) void fused2_kernel(
    const u16* __restrict__ xlr2, const int* __restrict__ row_start,
    const int* __restrict__ ssrc, const float* __restrict__ att2,
    const float* __restrict__ bias2, const float* __restrict__ Wa,
    const float* __restrict__ ba, const float* __restrict__ Wrc,
    const float* __restrict__ brc, float* __restrict__ out, int n) {
    int node = blockIdx.x * 4 + (threadIdx.x >> 6);
    int lane = threadIdx.x & 63;
    if (node >= n) return;

    unsigned int xr = *(const unsigned int*)(xlr2 + (size_t)node * 256 + 128 + lane * 2);
    float xr0 = bflo(xr), xr1 = bfhi(xr);
    float2 w = ((const float2*)att2)[lane];

    int beg = row_start[node], end = row_start[node + 1];
    float l = 0.f, acc0 = 0.f, acc1 = 0.f;

    unsigned int v0 = 0, v1 = 0;
    if (beg < end)     v0 = *(const unsigned int*)(xlr2 + (size_t)ssrc[beg] * 256 + lane * 2);
    if (beg + 1 < end) v1 = *(const unsigned int*)(xlr2 + (size_t)ssrc[beg + 1] * 256 + lane * 2);

    for (int p = beg; p < end; p += 2) {
        unsigned int c0 = v0, c1 = v1;
        if (p + 2 < end) v0 = *(const unsigned int*)(xlr2 + (size_t)ssrc[p + 2] * 256 + lane * 2);
        if (p + 3 < end) v1 = *(const unsigned int*)(xlr2 + (size_t)ssrc[p + 3] * 256 + lane * 2);

        float x0 = bflo(c0), x1 = bfhi(c0);
        float t0 = x0 + xr0, t1 = x1 + xr1;
        float sc = fmaxf(t0, 0.2f * t0) * w.x + fmaxf(t1, 0.2f * t1) * w.y;
        #pragma unroll
        for (int off = 1; off < 64; off <<= 1) sc += __shfl_xor(sc, off);
        float pv = __expf(sc);
        l += pv;
        acc0 = fmaf(pv, x0, acc0);
        acc1 = fmaf(pv, x1, acc1);

        if (p + 1 < end) {
            float y0 = bflo(c1), y1 = bfhi(c1);
            float u0 = y0 + xr0, u1 = y1 + xr1;
            float sc1 = fmaxf(u0, 0.2f * u0) * w.x + fmaxf(u1, 0.2f * u1) * w.y;
            #pragma unroll
            for (int off = 1; off < 64; off <<= 1) sc1 += __shfl_xor(sc1, off);
            float pv1 = __expf(sc1);
            l += pv1;
            acc0 = fmaf(pv1, y0, acc0);
            acc1 = fmaf(pv1, y1, acc1);
        }
    }

    float inv = 1.f / (l + 1e-16f);
    int c0i = lane * 2, c1i = lane * 2 + 1;
    float h0 = fmaf(acc0, inv, bias2[c0i]);
    float h1v = fmaf(acc1, inv, bias2[c1i]);
    float a = h0 * Wa[c0i] + h1v * Wa[c1i];
    float r = h0 * Wrc[c0i] + h1v * Wrc[c1i];
    #pragma unroll
    for (int off = 1; off < 64; off <<= 1) {
        a += __shfl_xor(a, off);
        r += __shfl_xor(r, off);
    }
    if (lane == 0) {
        out[node]     = 1.f / (1.f + __expf(-(a + ba[0])));
        out[n + node] = 1.f / (1.f + __expf(-(r + brc[0])));
    }
}

// ---------------------------------------------------------------------------
extern "C" void kernel_launch(void* const* d_in, const int* in_sizes, int n_in,
                              void* d_out, int out_size, void* d_ws, size_t ws_size,
                              hipStream_t stream) {
    const float* x    = (const float*)d_in[0];
    const int* ei     = (const int*)d_in[1];
    const float* W1l  = (const float*)d_in[2];
    const float* b1l  = (const float*)d_in[3];
    const float* W1r  = (const float*)d_in[4];
    const float* b1r  = (const float*)d_in[5];
    const float* att1 = (const float*)d_in[6];
    const float* bias1= (const float*)d_in[7];
    const float* W2l  = (const float*)d_in[8];
    const float* b2l  = (const float*)d_in[9];
    const float* W2r  = (const float*)d_in[10];
    const float* b2r  = (const float*)d_in[11];
    const float* att2 = (const float*)d_in[12];
    const float* bias2= (const float*)d_in[13];
    const float* Wa   = (const float*)d_in[14];
    const float* ba   = (const float*)d_in[15];
    const float* Wrc  = (const float*)d_in[16];
    const float* brc  = (const float*)d_in[17];
    float* out = (float*)d_out;

    const int N = N_NODES, E = N_EDGES;
    const int* src = ei;
    const int* dst = ei + E;

    char* ws = (char*)d_ws;
    u16*   xlr1 = (u16*)ws;                           // [MPAD][1024] bf16 = 41,156,608
    u16*   h1b  = (u16*)(ws + 41156608);              // [MPAD][512] bf16 = 20,578,304
    u16*   xb   = (u16*)(ws + 61734912);              // [MPAD][256] bf16 = 10,289,152
    u16*   xlr2 = (u16*)(ws + 61734912);              // reuses xb after gemm1
    u16*   BT1  = (u16*)(ws + 72024064);              // [1024][256] bf16 = 524,288
    u16*   BT2  = (u16*)(ws + 72548352);              // [256][512] bf16 = 262,144
    float* bc1  = (float*)(ws + 72810496);            // 4096
    float* bc2  = (float*)(ws + 72814592);            // 1024
    int* deg       = (int*)(ws + 72815616);           // 80,000
    int* row_start = (int*)(ws + 72896000);           // 80,004
    int* cursor    = (int*)(ws + 72976128);           // 80,000
    int* ssrc      = (int*)(ws + 73056128);           // 1,280,000
    int* seid      = (int*)(ws + 74336128);           // 1,280,000
    int* sdst      = (int*)(ws + 75616128);           // 1,280,000
    // end ~76.9 MB (89.8 MB proven available)

    // --- CSR build (deterministic via parallel rank) ---
    hipMemsetAsync(deg, 0, N * sizeof(int), stream);
    hist_kernel<<<(E + 255) / 256, 256, 0, stream>>>(dst, deg, E);
    scan_kernel<<<1, 1024, 0, stream>>>(deg, row_start, cursor, N);
    scatter_kernel<<<(E + 255) / 256, 256, 0, stream>>>(dst, cursor, seid, sdst, E);
    rank_kernel<<<(E + 255) / 256, 256, 0, stream>>>(row_start, seid, sdst, src, ssrc, E);

    // --- casts / weight prep ---
    cast_x_kernel<<<(MPAD * IN_DIM / 4 + 255) / 256, 256, 0, stream>>>(x, xb);
    transpose_all_kernel<<<dim3(16, 16, 4), dim3(32, 8), 0, stream>>>(
        W1l, W1r, W2l, W2r, BT1, BT2);
    prep_bias_kernel<<<1, 1024, 0, stream>>>(b1l, b1r, b2l, b2r, bc1, bc2);

    // --- layer 1 ---
    gemm_bf16_kernel<<<dim3(8, 157), 256, 0, stream>>>(xb, BT1, bc1, xlr1, 256, N, 1024);
    fused1_kernel<<<(N + 3) / 4, 256, 0, stream>>>(xlr1, row_start, ssrc, att1, bias1, h1b, N);

    // --- layer 2 + heads ---
    gemm_bf16_kernel<<<dim3(2, 157), 256, 0, stream>>>(h1b, BT2, bc2, xlr2, 512, N, 256);
    fused2_kernel<<<(N + 3) / 4, 256, 0, stream>>>(xlr2, row_start, ssrc, att2, bias2,
                                                   Wa, ba, Wrc, brc, out, N);
}

// Round 10
// 227.678 us; speedup vs baseline: 3.8267x; 1.1024x over previous
//
#include <hip/hip_runtime.h>
#include <hip/hip_bf16.h>

#define N_NODES 20000
#define N_EDGES 320000
#define IN_DIM 256
#define HID 128
#define HEADS 4
#define MPAD 20096   // 157 * 128

typedef unsigned short u16;
typedef __attribute__((ext_vector_type(8))) short bf16x8;
typedef __attribute__((ext_vector_type(4))) float f32x4;
typedef __attribute__((address_space(1))) void g_void;
typedef __attribute__((address_space(3))) void l_void;

__device__ __forceinline__ float asf(unsigned int u) {
    union { unsigned int i; float f; } c; c.i = u; return c.f;
}
__device__ __forceinline__ float bflo(unsigned int u) { return asf(u << 16); }
__device__ __forceinline__ float bfhi(unsigned int u) { return asf(u & 0xffff0000u); }
__device__ __forceinline__ u16 f2bf(float f) {
    union { float f; unsigned int i; } c; c.f = f;
    return (u16)((c.i + 0x7FFF + ((c.i >> 16) & 1)) >> 16);   // RNE
}
// bijective XCD swizzle (m204): consecutive-wg XCD round-robin -> contiguous
// wgid chunks per XCD, so same-brow column tiles share the XCD-local L2.
__device__ __forceinline__ int xcd_swz(int orig, int nwg) {
    int q = nwg >> 3, r = nwg & 7;
    int xcd = orig & 7, lin = orig >> 3;
    return (xcd < r ? xcd * (q + 1) : r * (q + 1) + (xcd - r) * q) + lin;
}

// ---------------------------------------------------------------------------
// CSR build: histogram -> scan -> scatter(eid,dst) -> parallel rank+fill
// Deterministic: final ssrc order within each segment is ascending edge id.
// ---------------------------------------------------------------------------
__global__ void hist_kernel(const int* __restrict__ dst, int* __restrict__ deg, int E) {
    int i = blockIdx.x * blockDim.x + threadIdx.x;
    if (i < E) atomicAdd(&deg[dst[i]], 1);
}

__global__ __launch_bounds__(1024) void scan_kernel(
    const int* __restrict__ deg, int* __restrict__ row_start,
    int* __restrict__ cursor, int n) {
    __shared__ int partial[1024];
    int t = threadIdx.x;
    int chunk = (n + 1023) / 1024;
    int begin = t * chunk;
    int end = min(begin + chunk, n);
    int s = 0;
    for (int i = begin; i < end; ++i) s += deg[i];
    partial[t] = s;
    __syncthreads();
    for (int off = 1; off < 1024; off <<= 1) {
        int v = (t >= off) ? partial[t - off] : 0;
        __syncthreads();
        partial[t] += v;
        __syncthreads();
    }
    int run = (t == 0) ? 0 : partial[t - 1];
    for (int i = begin; i < end; ++i) {
        row_start[i] = run;
        cursor[i] = run;
        run += deg[i];
    }
    if (t == 1023) row_start[n] = run;
}

__global__ void scatter_kernel(const int* __restrict__ dst, int* __restrict__ cursor,
                               int* __restrict__ seid, int* __restrict__ sdst, int E) {
    int i = blockIdx.x * blockDim.x + threadIdx.x;
    if (i < E) {
        int d = dst[i];
        int pos = atomicAdd(&cursor[d], 1);
        seid[pos] = i;
        sdst[pos] = d;
    }
}

__global__ void rank_kernel(const int* __restrict__ row_start, const int* __restrict__ seid,
                            const int* __restrict__ sdst, const int* __restrict__ src,
                            int* __restrict__ ssrc, int E) {
    int i = blockIdx.x * blockDim.x + threadIdx.x;
    if (i >= E) return;
    int d = sdst[i];
    int beg = row_start[d], end = row_start[d + 1];
    int my = seid[i];
    int rank = 0;
    for (int j = beg; j < end; ++j) rank += (seid[j] < my) ? 1 : 0;
    ssrc[beg + rank] = src[my];
}

// ---------------------------------------------------------------------------
// cast x (fp32 [20000][256]) -> bf16 [MPAD][256], pad rows zeroed
// ---------------------------------------------------------------------------
__global__ void cast_x_kernel(const float* __restrict__ x, u16* __restrict__ xb) {
    int i = blockIdx.x * blockDim.x + threadIdx.x;     // quad id
    const int nq = MPAD * IN_DIM / 4;
    if (i >= nq) return;
    int elem = i * 4;
    uint2 u;
    if (elem < N_NODES * IN_DIM) {
        float4 v = ((const float4*)x)[i];
        u.x = (unsigned)f2bf(v.x) | ((unsigned)f2bf(v.y) << 16);
        u.y = (unsigned)f2bf(v.z) | ((unsigned)f2bf(v.w) << 16);
    } else {
        u.x = 0u; u.y = 0u;
    }
    *(uint2*)(xb + elem) = u;
}

// ---------------------------------------------------------------------------
// transpose+cast all four weights: W fp32 [K][N] -> out bf16 [N][K]
// ---------------------------------------------------------------------------
__global__ __launch_bounds__(256) void transpose_all_kernel(
    const float* __restrict__ W1l, const float* __restrict__ W1r,
    const float* __restrict__ W2l, const float* __restrict__ W2r,
    u16* __restrict__ BT1, u16* __restrict__ BT2) {
    const float* W; u16* out; int K, N;
    switch (blockIdx.z) {
        case 0:  W = W1l; out = BT1;             K = 256; N = 512; break;
        case 1:  W = W1r; out = BT1 + 512 * 256; K = 256; N = 512; break;
        case 2:  W = W2l; out = BT2;             K = 512; N = 128; break;
        default: W = W2r; out = BT2 + 128 * 512; K = 512; N = 128; break;
    }
    int bx = blockIdx.x * 32;   // n base
    int by = blockIdx.y * 32;   // k base
    if (bx >= N || by >= K) return;
    __shared__ float t[32][33];
    int tx = threadIdx.x, ty = threadIdx.y;
    #pragma unroll
    for (int j = 0; j < 32; j += 8)
        t[ty + j][tx] = W[(size_t)(by + ty + j) * N + bx + tx];
    __syncthreads();
    #pragma unroll
    for (int j = 0; j < 32; j += 8)
        out[(size_t)(bx + ty + j) * K + by + tx] = f2bf(t[tx][ty + j]);
}

// ---------------------------------------------------------------------------
// concat biases (fp32)
// ---------------------------------------------------------------------------
__global__ void prep_bias_kernel(const float* b1l, const float* b1r,
                                 const float* b2l, const float* b2r,
                                 float* bc1, float* bc2) {
    int t = threadIdx.x;   // one block of 1024
    if (t < 512) bc1[t] = b1l[t];
    else bc1[t] = b1r[t - 512];
    if (t < 128) bc2[t] = b2l[t];
    else if (t < 256) bc2[t] = b2r[t - 128];
}

// ---------------------------------------------------------------------------
// bf16 MFMA GEMM: C[MPAD][N] = A[MPAD][K] @ BT[N][K]^T + bias, bf16 out
// tile 128x128, BK=32, 256 threads (4 waves 2x2), 4x4 16x16 frags per wave.
// 1-D grid, XCD-swizzled. Epilogue stages each 64x128 half-tile through LDS
// (XOR bank-swizzle) and stores coalesced bf16x8 rows (no write amplification).
// Stores ALL MPAD rows: pad-row outputs are never read downstream.
// ---------------------------------------------------------------------------
__global__ __launch_bounds__(256) void gemm_bf16_kernel(
    const u16* __restrict__ A, const u16* __restrict__ BT,
    const float* __restrict__ bias, u16* __restrict__ C,
    int K, int N, int nbx) {
    __shared__ u16 smem[8192];           // As[4096] | Bs[4096]; epilogue: 64x128
    u16* As = smem;
    u16* Bs = smem + 4096;
    const int tid = threadIdx.x;
    const int lane = tid & 63;
    const int wid = tid >> 6;
    const int wr = wid >> 1, wc = wid & 1;
    const int wg = xcd_swz(blockIdx.x, gridDim.x);
    const int brow = (wg / nbx) * 128, bcol = (wg % nbx) * 128;

    const int srow = tid >> 2;
    const int skk = (((tid & 3) ^ ((tid >> 3) & 3))) * 8;
    const u16* ga0 = A + (size_t)(brow + srow) * K + skk;
    const u16* ga1 = A + (size_t)(brow + 64 + srow) * K + skk;
    const u16* gb0 = BT + (size_t)(bcol + srow) * K + skk;
    const u16* gb1 = BT + (size_t)(bcol + 64 + srow) * K + skk;
    u16* lA0 = As + tid * 8;
    u16* lA1 = As + 2048 + tid * 8;
    u16* lB0 = Bs + tid * 8;
    u16* lB1 = Bs + 2048 + tid * 8;

    const int fr = lane & 15;
    const int fg = lane >> 4;
    const int fslot = (fg ^ ((fr >> 1) & 3)) * 8;
    const u16* ra = As + (wr * 64 + fr) * 32 + fslot;
    const u16* rb = Bs + (wc * 64 + fr) * 32 + fslot;

    f32x4 acc[4][4];
    #pragma unroll
    for (int m = 0; m < 4; ++m)
        #pragma unroll
        for (int n = 0; n < 4; ++n)
            acc[m][n] = (f32x4){0.f, 0.f, 0.f, 0.f};

    for (int k0 = 0; k0 < K; k0 += 32) {
        __builtin_amdgcn_global_load_lds((const g_void*)(ga0 + k0), (l_void*)lA0, 16, 0, 0);
        __builtin_amdgcn_global_load_lds((const g_void*)(ga1 + k0), (l_void*)lA1, 16, 0, 0);
        __builtin_amdgcn_global_load_lds((const g_void*)(gb0 + k0), (l_void*)lB0, 16, 0, 0);
        __builtin_amdgcn_global_load_lds((const g_void*)(gb1 + k0), (l_void*)lB1, 16, 0, 0);
        __syncthreads();
        bf16x8 av[4], bv[4];
        #pragma unroll
        for (int m = 0; m < 4; ++m) av[m] = *(const bf16x8*)(ra + m * 512);
        #pragma unroll
        for (int n = 0; n < 4; ++n) bv[n] = *(const bf16x8*)(rb + n * 512);
        #pragma unroll
        for (int m = 0; m < 4; ++m)
            #pragma unroll
            for (int n = 0; n < 4; ++n)
                acc[m][n] = __builtin_amdgcn_mfma_f32_16x16x32_bf16(av[m], bv[n], acc[m][n], 0, 0, 0);
        __syncthreads();
    }

    // epilogue: half-tile LDS repack, then coalesced bf16x8 row stores.
    float bv4[4];
    #pragma unroll
    for (int n = 0; n < 4; ++n) bv4[n] = bias[bcol + wc * 64 + n * 16 + fr];
    #pragma unroll
    for (int ph = 0; ph < 2; ++ph) {
        __syncthreads();
        if (wr == ph) {
            #pragma unroll
            for (int m = 0; m < 4; ++m)
                #pragma unroll
                for (int n = 0; n < 4; ++n) {
                    const int cc = wc * 64 + n * 16 + fr;
                    #pragma unroll
                    for (int j = 0; j < 4; ++j) {
                        const int rr = m * 16 + fg * 4 + j;
                        smem[rr * 128 + (cc ^ (((rr >> 2) & 3) << 4))] =
                            f2bf(acc[m][n][j] + bv4[n]);
                    }
                }
        }
        __syncthreads();
        #pragma unroll
        for (int it = 0; it < 4; ++it) {
            const int rr = it * 16 + (tid >> 4);
            const int cc0 = (tid & 15) * 8;
            *(bf16x8*)(C + (size_t)(brow + ph * 64 + rr) * N + bcol + cc0) =
                *(const bf16x8*)(smem + rr * 128 + (cc0 ^ (((rr >> 2) & 3) << 4)));
        }
    }
}

// ---------------------------------------------------------------------------
// fused layer-1 edge phase: one wave per node, no-shift softmax (scores are
// O(1); fp32 exp overflows only past 88). 2-edge unroll with dual prefetch.
// ---------------------------------------------------------------------------
#define UNPACK8(c, f) \
    f[0] = bflo(c.x); f[1] = bfhi(c.x); f[2] = bflo(c.y); f[3] = bfhi(c.y); \
    f[4] = bflo(c.z); f[5] = bfhi(c.z); f[6] = bflo(c.w); f[7] = bfhi(c.w);

__global__ __launch_bounds__(256) void fused1_kernel(
    const u16* __restrict__ xlr, const int* __restrict__ row_start,
    const int* __restrict__ ssrc, const float* __restrict__ att1,
    const float* __restrict__ bias1, u16* __restrict__ h1, int n) {
    int node = blockIdx.x * 4 + (threadIdx.x >> 6);
    int lane = threadIdx.x & 63;
    if (node >= n) return;

    uint4 xr4 = *(const uint4*)(xlr + (size_t)node * 1024 + 512 + lane * 8);
    float xrf[8];
    UNPACK8(xr4, xrf);
    float4 w0 = ((const float4*)att1)[lane * 2];
    float4 w1 = ((const float4*)att1)[lane * 2 + 1];
    float wa[8] = {w0.x, w0.y, w0.z, w0.w, w1.x, w1.y, w1.z, w1.w};

    int beg = row_start[node], end = row_start[node + 1];
    float l = 0.f;
    float acc[8] = {0.f, 0.f, 0.f, 0.f, 0.f, 0.f, 0.f, 0.f};

    uint4 v0 = {0, 0, 0, 0}, v1 = {0, 0, 0, 0};
    if (beg < end)     v0 = *(const uint4*)(xlr + (size_t)ssrc[beg] * 1024 + lane * 8);
    if (beg + 1 < end) v1 = *(const uint4*)(xlr + (size_t)ssrc[beg + 1] * 1024 + lane * 8);

    for (int p = beg; p < end; p += 2) {
        uint4 c0 = v0, c1 = v1;
        if (p + 2 < end) v0 = *(const uint4*)(xlr + (size_t)ssrc[p + 2] * 1024 + lane * 8);
        if (p + 3 < end) v1 = *(const uint4*)(xlr + (size_t)ssrc[p + 3] * 1024 + lane * 8);

        float xf[8];
        UNPACK8(c0, xf);
        float sc = 0.f;
        #pragma unroll
        for (int j = 0; j < 8; ++j) {
            float v = xf[j] + xrf[j];
            sc = fmaf(fmaxf(v, 0.2f * v), wa[j], sc);
        }
        sc += __shfl_xor(sc, 1);
        sc += __shfl_xor(sc, 2);
        sc += __shfl_xor(sc, 4);
        sc += __shfl_xor(sc, 8);
        float pv = __expf(sc);
        l += pv;
        #pragma unroll
        for (int j = 0; j < 8; ++j) acc[j] = fmaf(pv, xf[j], acc[j]);

        if (p + 1 < end) {
            float yf[8];
            UNPACK8(c1, yf);
            float sc1 = 0.f;
            #pragma unroll
            for (int j = 0; j < 8; ++j) {
                float v = yf[j] + xrf[j];
                sc1 = fmaf(fmaxf(v, 0.2f * v), wa[j], sc1);
            }
            sc1 += __shfl_xor(sc1, 1);
            sc1 += __shfl_xor(sc1, 2);
            sc1 += __shfl_xor(sc1, 4);
            sc1 += __shfl_xor(sc1, 8);
            float pv1 = __expf(sc1);
            l += pv1;
            #pragma unroll
            for (int j = 0; j < 8; ++j) acc[j] = fmaf(pv1, yf[j], acc[j]);
        }
    }

    float inv = 1.f / (l + 1e-16f);
    float4 b0 = ((const float4*)bias1)[lane * 2];
    float4 b1 = ((const float4*)bias1)[lane * 2 + 1];
    float bb[8] = {b0.x, b0.y, b0.z, b0.w, b1.x, b1.y, b1.z, b1.w};
    bf16x8 outv;
    #pragma unroll
    for (int j = 0; j < 8; ++j) {
        float v = fmaf(acc[j], inv, bb[j]);
        v = v > 0.f ? v : __expf(v) - 1.f;   // ELU
        outv[j] = (short)f2bf(v);
    }
    *(bf16x8*)(h1 + (size_t)node * 512 + lane * 8) = outv;
}

// ---------------------------------------------------------------------------
// fused layer-2 edge phase + heads: one wave per node, no-shift softmax,
// 2-edge unroll, then anomaly/root-cause dots + sigmoid.
// ---------------------------------------------------------------------------
__global__ __launch_bounds__(256) void fused2_kernel(
    const u16* __restrict__ xlr2, const int* __restrict__ row_start,
    const int* __restrict__ ssrc, const float* __restrict__ att2,
    const float* __restrict__ bias2, const float* __restrict__ Wa,
    const float* __restrict__ ba, const float* __restrict__ Wrc,
    const float* __restrict__ brc, float* __restrict__ out, int n) {
    int node = blockIdx.x * 4 + (threadIdx.x >> 6);
    int lane = threadIdx.x & 63;
    if (node >= n) return;

    unsigned int xr = *(const unsigned int*)(xlr2 + (size_t)node * 256 + 128 + lane * 2);
    float xr0 = bflo(xr), xr1 = bfhi(xr);
    float2 w = ((const float2*)att2)[lane];

    int beg = row_start[node], end = row_start[node + 1];
    float l = 0.f, acc0 = 0.f, acc1 = 0.f;

    unsigned int v0 = 0, v1 = 0;
    if (beg < end)     v0 = *(const unsigned int*)(xlr2 + (size_t)ssrc[beg] * 256 + lane * 2);
    if (beg + 1 < end) v1 = *(const unsigned int*)(xlr2 + (size_t)ssrc[beg + 1] * 256 + lane * 2);

    for (int p = beg; p < end; p += 2) {
        unsigned int c0 = v0, c1 = v1;
        if (p + 2 < end) v0 = *(const unsigned int*)(xlr2 + (size_t)ssrc[p + 2] * 256 + lane * 2);
        if (p + 3 < end) v1 = *(const unsigned int*)(xlr2 + (size_t)ssrc[p + 3] * 256 + lane * 2);

        float x0 = bflo(c0), x1 = bfhi(c0);
        float t0 = x0 + xr0, t1 = x1 + xr1;
        float sc = fmaxf(t0, 0.2f * t0) * w.x + fmaxf(t1, 0.2f * t1) * w.y;
        #pragma unroll
        for (int off = 1; off < 64; off <<= 1) sc += __shfl_xor(sc, off);
        float pv = __expf(sc);
        l += pv;
        acc0 = fmaf(pv, x0, acc0);
        acc1 = fmaf(pv, x1, acc1);

        if (p + 1 < end) {
            float y0 = bflo(c1), y1 = bfhi(c1);
            float u0 = y0 + xr0, u1 = y1 + xr1;
            float sc1 = fmaxf(u0, 0.2f * u0) * w.x + fmaxf(u1, 0.2f * u1) * w.y;
            #pragma unroll
            for (int off = 1; off < 64; off <<= 1) sc1 += __shfl_xor(sc1, off);
            float pv1 = __expf(sc1);
            l += pv1;
            acc0 = fmaf(pv1, y0, acc0);
            acc1 = fmaf(pv1, y1, acc1);
        }
    }

    float inv = 1.f / (l + 1e-16f);
    int c0i = lane * 2, c1i = lane * 2 + 1;
    float h0 = fmaf(acc0, inv, bias2[c0i]);
    float h1v = fmaf(acc1, inv, bias2[c1i]);
    float a = h0 * Wa[c0i] + h1v * Wa[c1i];
    float r = h0 * Wrc[c0i] + h1v * Wrc[c1i];
    #pragma unroll
    for (int off = 1; off < 64; off <<= 1) {
        a += __shfl_xor(a, off);
        r += __shfl_xor(r, off);
    }
    if (lane == 0) {
        out[node]     = 1.f / (1.f + __expf(-(a + ba[0])));
        out[n + node] = 1.f / (1.f + __expf(-(r + brc[0])));
    }
}

// ---------------------------------------------------------------------------
extern "C" void kernel_launch(void* const* d_in, const int* in_sizes, int n_in,
                              void* d_out, int out_size, void* d_ws, size_t ws_size,
                              hipStream_t stream) {
    const float* x    = (const float*)d_in[0];
    const int* ei     = (const int*)d_in[1];
    const float* W1l  = (const float*)d_in[2];
    const float* b1l  = (const float*)d_in[3];
    const float* W1r  = (const float*)d_in[4];
    const float* b1r  = (const float*)d_in[5];
    const float* att1 = (const float*)d_in[6];
    const float* bias1= (const float*)d_in[7];
    const float* W2l  = (const float*)d_in[8];
    const float* b2l  = (const float*)d_in[9];
    const float* W2r  = (const float*)d_in[10];
    const float* b2r  = (const float*)d_in[11];
    const float* att2 = (const float*)d_in[12];
    const float* bias2= (const float*)d_in[13];
    const float* Wa   = (const float*)d_in[14];
    const float* ba   = (const float*)d_in[15];
    const float* Wrc  = (const float*)d_in[16];
    const float* brc  = (const float*)d_in[17];
    float* out = (float*)d_out;

    const int N = N_NODES, E = N_EDGES;
    const int* src = ei;
    const int* dst = ei + E;

    char* ws = (char*)d_ws;
    u16*   xlr1 = (u16*)ws;                           // [MPAD][1024] bf16 = 41,156,608
    u16*   h1b  = (u16*)(ws + 41156608);              // [MPAD][512] bf16 = 20,578,304
    u16*   xb   = (u16*)(ws + 61734912);              // [MPAD][256] bf16 = 10,289,152
    u16*   xlr2 = (u16*)(ws + 61734912);              // reuses xb after gemm1
    u16*   BT1  = (u16*)(ws + 72024064);              // [1024][256] bf16 = 524,288
    u16*   BT2  = (u16*)(ws + 72548352);              // [256][512] bf16 = 262,144
    float* bc1  = (float*)(ws + 72810496);            // 4096
    float* bc2  = (float*)(ws + 72814592);            // 1024
    int* deg       = (int*)(ws + 72815616);           // 80,000
    int* row_start = (int*)(ws + 72896000);           // 80,004
    int* cursor    = (int*)(ws + 72976128);           // 80,000
    int* ssrc      = (int*)(ws + 73056128);           // 1,280,000
    int* seid      = (int*)(ws + 74336128);           // 1,280,000
    int* sdst      = (int*)(ws + 75616128);           // 1,280,000
    // end ~76.9 MB (89.8 MB proven available)

    // --- CSR build (deterministic via parallel rank) ---
    hipMemsetAsync(deg, 0, N * sizeof(int), stream);
    hist_kernel<<<(E + 255) / 256, 256, 0, stream>>>(dst, deg, E);
    scan_kernel<<<1, 1024, 0, stream>>>(deg, row_start, cursor, N);
    scatter_kernel<<<(E + 255) / 256, 256, 0, stream>>>(dst, cursor, seid, sdst, E);
    rank_kernel<<<(E + 255) / 256, 256, 0, stream>>>(row_start, seid, sdst, src, ssrc, E);

    // --- casts / weight prep ---
    cast_x_kernel<<<(MPAD * IN_DIM / 4 + 255) / 256, 256, 0, stream>>>(x, xb);
    transpose_all_kernel<<<dim3(16, 16, 4), dim3(32, 8), 0, stream>>>(
        W1l, W1r, W2l, W2r, BT1, BT2);
    prep_bias_kernel<<<1, 1024, 0, stream>>>(b1l, b1r, b2l, b2r, bc1, bc2);

    // --- layer 1 ---
    gemm_bf16_kernel<<<157 * 8, 256, 0, stream>>>(xb, BT1, bc1, xlr1, 256, 1024, 8);
    fused1_kernel<<<(N + 3) / 4, 256, 0, stream>>>(xlr1, row_start, ssrc, att1, bias1, h1b, N);

    // --- layer 2 + heads ---
    gemm_bf16_kernel<<<157 * 2, 256, 0, stream>>>(h1b, BT2, bc2, xlr2, 512, 256, 2);
    fused2_kernel<<<(N + 3) / 4, 256, 0, stream>>>(xlr2, row_start, ssrc, att2, bias2,
                                                   Wa, ba, Wrc, brc, out, N);
}